// Round 3
// baseline (612.094 us; speedup 1.0000x reference)
//
#include <hip/hip_runtime.h>
#include <math.h>

#define LI 2048
#define LT 384
#define LSEQ 2432
#define DM 2560
#define NH 20
#define DH 128
#define SCALE 0.08838834764831845f

typedef __bf16 bf16x8 __attribute__((ext_vector_type(8)));
typedef __bf16 bf16x4 __attribute__((ext_vector_type(4)));
typedef __bf16 bf16x2 __attribute__((ext_vector_type(2)));
typedef float f32x4 __attribute__((ext_vector_type(4)));

__device__ __forceinline__ void async_copy16(const void* gsrc, void* lds_uniform) {
    __builtin_amdgcn_global_load_lds(
        (const __attribute__((address_space(1))) unsigned int*)gsrc,
        (__attribute__((address_space(3))) unsigned int*)lds_uniform,
        16, 0, 0);
}

// ---------------- f32 -> bf16 conversions ----------------

__global__ __launch_bounds__(256) void cvt8_kernel(
    const float* __restrict__ s0, const float* __restrict__ s1,
    const float* __restrict__ s2, const float* __restrict__ s3,
    const float* __restrict__ s4, const float* __restrict__ s5,
    const float* __restrict__ s6, const float* __restrict__ s7,
    __bf16* __restrict__ dst)
{
    const float* srcs[8] = {s0, s1, s2, s3, s4, s5, s6, s7};
    const float* s = srcs[blockIdx.y];
    __bf16* d = dst + (size_t)blockIdx.y * (size_t)DM * DM;
    int i = blockIdx.x * 256 + threadIdx.x;
    const float4* sp = (const float4*)s + (size_t)i * 2;
    float4 a = sp[0], b = sp[1];
    bf16x8 o = {(__bf16)a.x, (__bf16)a.y, (__bf16)a.z, (__bf16)a.w,
                (__bf16)b.x, (__bf16)b.y, (__bf16)b.z, (__bf16)b.w};
    *((bf16x8*)d + i) = o;
}

__global__ __launch_bounds__(256) void cvt_kernel(
    const float* __restrict__ s, __bf16* __restrict__ d, int n8)
{
    int i = blockIdx.x * 256 + threadIdx.x;
    if (i >= n8) return;
    const float4* sp = (const float4*)s + (size_t)i * 2;
    float4 a = sp[0], b = sp[1];
    bf16x8 o = {(__bf16)a.x, (__bf16)a.y, (__bf16)a.z, (__bf16)a.w,
                (__bf16)b.x, (__bf16)b.y, (__bf16)b.z, (__bf16)b.w};
    *((bf16x8*)d + i) = o;
}

// ---------------- 128x128 bf16 GEMM core, BK=64, XOR-swizzled LDS ----------------
// C = A @ B^T + bias (f32 out). A: (M,2560), B: (N,2560) bf16 row-major.
// LDS tiles 128x64, 8 16B-units per row; physical unit = logical ^ (row&7).

__device__ __forceinline__ void gemm_core(
    const __bf16* __restrict__ Ab,    // A + m0*2560
    const __bf16* __restrict__ Bb,    // B + n_local*2560
    const float* __restrict__ bias,   // + n_local
    float* __restrict__ Cb,           // C + m0*2560 + n_local (ld = 2560)
    __bf16* sA, __bf16* sB)
{
    const int t = threadIdx.x, wave = t >> 6, lane = t & 63;
    const int l15 = lane & 15, quad = lane >> 4;
    const int wm = wave >> 1, wn = wave & 1;

    f32x4 acc[4][4];
#pragma unroll
    for (int i = 0; i < 4; i++)
#pragma unroll
        for (int j = 0; j < 4; j++) acc[i][j] = f32x4{0.f, 0.f, 0.f, 0.f};

    // staging source offsets (swizzle inverted): unit c = j*256 + t
    size_t soff[4];
#pragma unroll
    for (int j = 0; j < 4; j++) {
        int c = j * 256 + t;
        int row = c >> 3, u = c & 7;
        soff[j] = (size_t)row * DM + ((u ^ (row & 7)) * 8);
    }

    for (int k0 = 0; k0 < DM; k0 += 64) {
        __syncthreads();
#pragma unroll
        for (int j = 0; j < 4; j++)
            async_copy16(Ab + soff[j] + k0, (char*)sA + (j * 256 + wave * 64) * 16);
#pragma unroll
        for (int j = 0; j < 4; j++)
            async_copy16(Bb + soff[j] + k0, (char*)sB + (j * 256 + wave * 64) * 16);
        __syncthreads();

#pragma unroll
        for (int ks = 0; ks < 2; ks++) {
            bf16x8 af[4], bg[4];
#pragma unroll
            for (int mt = 0; mt < 4; mt++) {
                int r = wm * 64 + mt * 16 + l15;
                af[mt] = *(const bf16x8*)(sA + r * 64 + (((quad + ks * 4) ^ (r & 7)) * 8));
            }
#pragma unroll
            for (int nt = 0; nt < 4; nt++) {
                int r = wn * 64 + nt * 16 + l15;
                bg[nt] = *(const bf16x8*)(sB + r * 64 + (((quad + ks * 4) ^ (r & 7)) * 8));
            }
#pragma unroll
            for (int mt = 0; mt < 4; mt++)
#pragma unroll
                for (int nt = 0; nt < 4; nt++)
                    acc[mt][nt] = __builtin_amdgcn_mfma_f32_16x16x32_bf16(af[mt], bg[nt], acc[mt][nt], 0, 0, 0);
        }
    }

#pragma unroll
    for (int mt = 0; mt < 4; mt++) {
        const int row = wm * 64 + mt * 16 + quad * 4;
#pragma unroll
        for (int nt = 0; nt < 4; nt++) {
            const int col = wn * 64 + nt * 16 + l15;
            const float bv = bias[col];
            float* cp = Cb + (size_t)row * DM + col;
            cp[0]        = acc[mt][nt][0] + bv;
            cp[DM]       = acc[mt][nt][1] + bv;
            cp[2 * DM]   = acc[mt][nt][2] + bv;
            cp[3 * DM]   = acc[mt][nt][3] + bv;
        }
    }
}

// QKV body shared by the two split dispatches (R0 mapping: n fastest).
__device__ __forceinline__ void qkv_body(
    int nblk, int mblk,
    const __bf16* __restrict__ xbf, const __bf16* __restrict__ wbf,
    const float* __restrict__ bq, const float* __restrict__ bk, const float* __restrict__ bv,
    const float* __restrict__ bq_t, const float* __restrict__ bk_t, const float* __restrict__ bv_t,
    float* __restrict__ qraw, float* __restrict__ kraw, float* __restrict__ vraw,
    __bf16* sA, __bf16* sB)
{
    const int which = nblk / 20;               // 0=Q 1=K 2=V
    const int nloc = (nblk % 20) * 128;
    const bool is_txt = (mblk >= 16);
    const size_t WELEM = (size_t)DM * DM;
    const int widx = which + (is_txt ? 4 : 0);
    const __bf16* W = wbf + (size_t)widx * WELEM;
    const float* bias = (which == 0) ? (is_txt ? bq_t : bq)
                      : (which == 1) ? (is_txt ? bk_t : bk)
                                     : (is_txt ? bv_t : bv);
    float* C = (which == 0) ? qraw : (which == 1) ? kraw : vraw;
    gemm_core(xbf + (size_t)mblk * 128 * DM, W + (size_t)nloc * DM, bias + nloc,
              C + (size_t)mblk * 128 * DM + nloc, sA, sB);
}

// QKV split for observability: a = mblk 0..9, b = mblk 10..18.
__global__ __launch_bounds__(256, 4) void gemm_qkv_a_kernel(
    const __bf16* __restrict__ xbf, const __bf16* __restrict__ wbf,
    const float* __restrict__ bq, const float* __restrict__ bk, const float* __restrict__ bv,
    const float* __restrict__ bq_t, const float* __restrict__ bk_t, const float* __restrict__ bv_t,
    float* __restrict__ qraw, float* __restrict__ kraw, float* __restrict__ vraw)
{
    __shared__ alignas(16) __bf16 sA[128 * 64];
    __shared__ alignas(16) __bf16 sB[128 * 64];
    qkv_body(blockIdx.x, blockIdx.y, xbf, wbf, bq, bk, bv, bq_t, bk_t, bv_t,
             qraw, kraw, vraw, sA, sB);
}

__global__ __launch_bounds__(256, 4) void gemm_qkv_b_kernel(
    const __bf16* __restrict__ xbf, const __bf16* __restrict__ wbf,
    const float* __restrict__ bq, const float* __restrict__ bk, const float* __restrict__ bv,
    const float* __restrict__ bq_t, const float* __restrict__ bk_t, const float* __restrict__ bv_t,
    float* __restrict__ qraw, float* __restrict__ kraw, float* __restrict__ vraw)
{
    __shared__ alignas(16) __bf16 sA[128 * 64];
    __shared__ alignas(16) __bf16 sB[128 * 64];
    qkv_body(blockIdx.x, blockIdx.y + 10, xbf, wbf, bq, bk, bv, bq_t, bk_t, bv_t,
             qraw, kraw, vraw, sA, sB);
}

// Out-proj: grid (20, 19), R0 mapping.
__global__ __launch_bounds__(256, 4) void gemm_out_kernel(
    const __bf16* __restrict__ attnbf, const __bf16* __restrict__ wbf,
    const float* __restrict__ bo, const float* __restrict__ bo_t,
    float* __restrict__ out)
{
    __shared__ alignas(16) __bf16 sA[128 * 64];
    __shared__ alignas(16) __bf16 sB[128 * 64];
    const int nblk = blockIdx.x, mblk = blockIdx.y;
    const bool is_txt = (mblk >= 16);
    const size_t WELEM = (size_t)DM * DM;
    const __bf16* W = wbf + (size_t)(is_txt ? 7 : 3) * WELEM;
    const float* bias = (is_txt ? bo_t : bo) + nblk * 128;
    gemm_core(attnbf + (size_t)mblk * 128 * DM, W + (size_t)nblk * 128 * DM, bias,
              out + (size_t)mblk * 128 * DM + nblk * 128, sA, sB);
}

// ---------------- RMS norm + qn/kn + mask + RoPE, f32 -> bf16 ----------------

__global__ __launch_bounds__(256) void rmsrope_kernel(
    const float* __restrict__ qraw, const float* __restrict__ kraw,
    const float* __restrict__ rope, const float* __restrict__ img_masks,
    const float* __restrict__ qn, const float* __restrict__ kn,
    const float* __restrict__ qn_t, const float* __restrict__ kn_t,
    __bf16* __restrict__ qbf, __bf16* __restrict__ kbf)
{
    const int l = blockIdx.x, t = threadIdx.x;
    const int wave = t >> 6, lane = t & 63;
    const bool is_img = (l < LI);
    const float* qw = is_img ? qn : qn_t;
    const float* kw = is_img ? kn : kn_t;
    const float kmask = is_img ? img_masks[l] : 1.0f;
    const float* qr = qraw + (size_t)l * DM;
    const float* kr = kraw + (size_t)l * DM;

    float2 qv[5], kv[5];
    float sq = 0.f, sk = 0.f;
#pragma unroll
    for (int j = 0; j < 5; j++) {
        int c2 = j * 256 + t;
        qv[j] = *(const float2*)(qr + 2 * c2);
        kv[j] = *(const float2*)(kr + 2 * c2);
        sq += qv[j].x * qv[j].x + qv[j].y * qv[j].y;
        sk += kv[j].x * kv[j].x + kv[j].y * kv[j].y;
    }
#pragma unroll
    for (int m = 32; m; m >>= 1) { sq += __shfl_xor(sq, m); sk += __shfl_xor(sk, m); }
    __shared__ float redq[4], redk[4];
    if (lane == 0) { redq[wave] = sq; redk[wave] = sk; }
    __syncthreads();
    sq = redq[0] + redq[1] + redq[2] + redq[3];
    sk = redk[0] + redk[1] + redk[2] + redk[3];
    const float rq = rsqrtf(sq * (1.0f / DM) + 1e-5f);
    const float rk = rsqrtf(sk * (1.0f / DM) + 1e-5f) * kmask;

#pragma unroll
    for (int j = 0; j < 5; j++) {
        int c2 = j * 256 + t;
        int c = 2 * c2;
        float4 rp = *(const float4*)(rope + ((size_t)l * 64 + (c2 & 63)) * 4);
        float2 w2q = *(const float2*)(qw + c);
        float2 w2k = *(const float2*)(kw + c);
        float x0 = qv[j].x * rq * w2q.x, x1 = qv[j].y * rq * w2q.y;
        bf16x2 oq = {(__bf16)(rp.x * x0 + rp.y * x1), (__bf16)(rp.z * x0 + rp.w * x1)};
        *(bf16x2*)(qbf + (size_t)l * DM + c) = oq;
        float y0 = kv[j].x * rk * w2k.x, y1 = kv[j].y * rk * w2k.y;
        bf16x2 ok = {(__bf16)(rp.x * y0 + rp.y * y1), (__bf16)(rp.z * y0 + rp.w * y1)};
        *(bf16x2*)(kbf + (size_t)l * DM + c) = ok;
    }
}

// ---------------- transpose V (L,DM) f32 -> (DM,L) bf16 ----------------

__global__ __launch_bounds__(256) void transpose_cvt_kernel(
    const float* __restrict__ src, __bf16* __restrict__ dst)
{
    __shared__ float tile[32][33];
    const int c0 = blockIdx.x * 32;
    const int r0 = blockIdx.y * 32;
    const int tc = threadIdx.x & 31, tr = threadIdx.x >> 5;
#pragma unroll
    for (int j = 0; j < 4; j++)
        tile[tr + j * 8][tc] = src[(size_t)(r0 + tr + j * 8) * DM + c0 + tc];
    __syncthreads();
#pragma unroll
    for (int j = 0; j < 4; j++)
        dst[(size_t)(c0 + tr + j * 8) * LSEQ + r0 + tc] = (__bf16)tile[tc][tr + j * 8];
}

// ---------------- flash attention ----------------
// T14 async-stage: K/V tile tau+1 preloaded into VGPRs right after tile tau's
// LDS writes; HBM/L3 latency hides under QK^T+softmax+PV. Reg->LDS writes land
// on the exact bytes global_load_lds used to write -> LDS contents bit-identical.

__global__ __launch_bounds__(256, 4) void flash_kernel(
    const __bf16* __restrict__ qb, const __bf16* __restrict__ kb,
    const __bf16* __restrict__ vt, __bf16* __restrict__ ob)
{
    __shared__ alignas(16) __bf16 sK[64 * DH];      // [kv 64][d 128]
    __shared__ alignas(16) __bf16 sV[DH * 64];      // [d 128][kv 64]
    __shared__ alignas(16) __bf16 sP[4 * 16 * 64];  // per-wave [q 16][kv 64]
    const int head = blockIdx.x;
    const int q0 = blockIdx.y * 64;
    const int t = threadIdx.x, wave = t >> 6, lane = t & 63;
    const int l15 = lane & 15, quad = lane >> 4;
    const int qrow = q0 + wave * 16 + l15;

    bf16x8 aq[4];
#pragma unroll
    for (int d = 0; d < 4; d++)
        aq[d] = *(const bf16x8*)(qb + (size_t)qrow * DM + head * DH + d * 32 + quad * 8);

    // 32-bit source offsets (buffers < 2^31 B); swizzle pre-inverted on source side
    int koff[4], voff[4];
#pragma unroll
    for (int j = 0; j < 4; j++) {
        int ck = (wave * 4 + j) * 64 + lane;
        int krow = ck >> 4, ku = (ck & 15) ^ (krow & 7);
        koff[j] = krow * DM + head * DH + ku * 8;
        int cv = (wave * 4 + j) * 64 + lane;
        int vrow = cv >> 3, vu = (cv & 7) ^ (vrow & 7);
        voff[j] = (head * DH + vrow) * LSEQ + vu * 8;
    }
    // LDS dest bytes = (wave*4+j)*1024 + lane*16 (matches global_load_lds layout)
    char* const dK = (char*)sK + wave * 4096 + lane * 16;
    char* const dV = (char*)sV + wave * 4096 + lane * 16;

    f32x4 o[8];
#pragma unroll
    for (int i = 0; i < 8; i++) o[i] = f32x4{0.f, 0.f, 0.f, 0.f};
    float m_i = -INFINITY, l_i = 0.f;
    __bf16* pw = sP + wave * (16 * 64);

    // preload tile 0 into regs
    bf16x8 rk[4], rv[4];
#pragma unroll
    for (int j = 0; j < 4; j++) {
        rk[j] = *(const bf16x8*)(kb + koff[j]);
        rv[j] = *(const bf16x8*)(vt + voff[j]);
    }

    for (int kv0 = 0; kv0 < LSEQ; kv0 += 64) {
        __syncthreads();                 // prev tile's LDS reads complete
#pragma unroll
        for (int j = 0; j < 4; j++) {
            *(bf16x8*)(dK + j * 1024) = rk[j];
            *(bf16x8*)(dV + j * 1024) = rv[j];
        }
        __syncthreads();                 // writes visible (lgkm drain only; no vmcnt)

        // issue next tile's loads now; they complete under the compute below
        if (kv0 + 64 < LSEQ) {
#pragma unroll
            for (int j = 0; j < 4; j++) {
                rk[j] = *(const bf16x8*)(kb + koff[j] + (size_t)(kv0 + 64) * DM);
                rv[j] = *(const bf16x8*)(vt + voff[j] + (kv0 + 64));
            }
        }

        f32x4 st[4];
        __builtin_amdgcn_s_setprio(1);
#pragma unroll
        for (int b = 0; b < 4; b++) {
            st[b] = f32x4{0.f, 0.f, 0.f, 0.f};
#pragma unroll
            for (int d = 0; d < 4; d++) {
                int row = b * 16 + l15;
                bf16x8 ak = *(const bf16x8*)(sK + row * 128 + (((d * 4 + quad) ^ (row & 7)) * 8));
                st[b] = __builtin_amdgcn_mfma_f32_16x16x32_bf16(ak, aq[d], st[b], 0, 0, 0);
            }
        }
        __builtin_amdgcn_s_setprio(0);

        float mx = m_i;
#pragma unroll
        for (int b = 0; b < 4; b++)
#pragma unroll
            for (int r = 0; r < 4; r++) { st[b][r] *= SCALE; mx = fmaxf(mx, st[b][r]); }
        mx = fmaxf(mx, __shfl_xor(mx, 16));
        mx = fmaxf(mx, __shfl_xor(mx, 32));
        const float al = __expf(m_i - mx);
        m_i = mx;
        float sum = 0.f;
#pragma unroll
        for (int b = 0; b < 4; b++)
#pragma unroll
            for (int r = 0; r < 4; r++) {
                float p = __expf(st[b][r] - mx);
                st[b][r] = p;
                sum += p;
            }
        sum += __shfl_xor(sum, 16);
        sum += __shfl_xor(sum, 32);
        l_i = l_i * al + sum;

#pragma unroll
        for (int b = 0; b < 4; b++) {
            bf16x4 pk = {(__bf16)st[b][0], (__bf16)st[b][1], (__bf16)st[b][2], (__bf16)st[b][3]};
            int u = 2 * b + (quad >> 1);
            *(bf16x4*)(pw + l15 * 64 + ((u ^ (l15 & 7)) * 8) + (quad & 1) * 4) = pk;
        }

        float alr[4];
#pragma unroll
        for (int r = 0; r < 4; r++) alr[r] = __shfl(al, quad * 4 + r);
#pragma unroll
        for (int i = 0; i < 8; i++) {
            f32x4 tmp = o[i];
            tmp[0] *= alr[0]; tmp[1] *= alr[1]; tmp[2] *= alr[2]; tmp[3] *= alr[3];
            o[i] = tmp;
        }
        __asm__ volatile("s_waitcnt lgkmcnt(0)" ::: "memory");

        bf16x8 ap0 = *(const bf16x8*)(pw + l15 * 64 + ((quad ^ (l15 & 7)) * 8));
        bf16x8 ap1 = *(const bf16x8*)(pw + l15 * 64 + (((4 + quad) ^ (l15 & 7)) * 8));
        __builtin_amdgcn_s_setprio(1);
#pragma unroll
        for (int n2 = 0; n2 < 8; n2++) {
            int row = n2 * 16 + l15;
            bf16x8 bv0 = *(const bf16x8*)(sV + row * 64 + ((quad ^ (row & 7)) * 8));
            bf16x8 bv1 = *(const bf16x8*)(sV + row * 64 + (((4 + quad) ^ (row & 7)) * 8));
            o[n2] = __builtin_amdgcn_mfma_f32_16x16x32_bf16(ap0, bv0, o[n2], 0, 0, 0);
            o[n2] = __builtin_amdgcn_mfma_f32_16x16x32_bf16(ap1, bv1, o[n2], 0, 0, 0);
        }
        __builtin_amdgcn_s_setprio(0);
    }

    const float inv = 1.0f / l_i;
    float invr[4];
#pragma unroll
    for (int r = 0; r < 4; r++) invr[r] = __shfl(inv, quad * 4 + r);
#pragma unroll
    for (int n2 = 0; n2 < 8; n2++)
#pragma unroll
        for (int r = 0; r < 4; r++)
            ob[(size_t)(q0 + wave * 16 + quad * 4 + r) * DM + head * DH + n2 * 16 + l15] =
                (__bf16)(o[n2][r] * invr[r]);
}

// ---------------- launch ----------------

extern "C" void kernel_launch(void* const* d_in, const int* in_sizes, int n_in,
                              void* d_out, int out_size, void* d_ws, size_t ws_size,
                              hipStream_t stream) {
    const float* img       = (const float*)d_in[0];
    const float* txt       = (const float*)d_in[1];
    const float* rope      = (const float*)d_in[2];
    const float* img_masks = (const float*)d_in[3];
    const float* Wq   = (const float*)d_in[4];  const float* bq   = (const float*)d_in[5];
    const float* Wk   = (const float*)d_in[6];  const float* bk   = (const float*)d_in[7];
    const float* Wv   = (const float*)d_in[8];  const float* bv   = (const float*)d_in[9];
    const float* Wo   = (const float*)d_in[10]; const float* bo   = (const float*)d_in[11];
    const float* Wq_t = (const float*)d_in[12]; const float* bq_t = (const float*)d_in[13];
    const float* Wk_t = (const float*)d_in[14]; const float* bk_t = (const float*)d_in[15];
    const float* Wv_t = (const float*)d_in[16]; const float* bv_t = (const float*)d_in[17];
    const float* Wo_t = (const float*)d_in[18]; const float* bo_t = (const float*)d_in[19];
    const float* qn   = (const float*)d_in[20]; const float* kn   = (const float*)d_in[21];
    const float* qn_t = (const float*)d_in[22]; const float* kn_t = (const float*)d_in[23];
    float* out = (float*)d_out;

    const size_t WELEM = (size_t)DM * DM;
    const size_t XELEM = (size_t)LSEQ * DM;

    __bf16* wbf  = (__bf16*)d_ws;
    __bf16* xbf  = wbf + 8 * WELEM;
    float*  qraw = (float*)(xbf + XELEM);
    float*  kraw = qraw + XELEM;
    float*  vraw = kraw + XELEM;
    __bf16* qbf  = (__bf16*)(vraw + XELEM);
    __bf16* kbf  = qbf + XELEM;
    __bf16* vt   = kbf + XELEM;
    __bf16* attnbf = (__bf16*)qraw;                // reuse (qraw dead after rmsrope)

    cvt8_kernel<<<dim3((int)(WELEM / 8 / 256), 8), 256, 0, stream>>>(
        Wq, Wk, Wv, Wo, Wq_t, Wk_t, Wv_t, Wo_t, wbf);
    cvt_kernel<<<dim3((LI * DM / 8 + 255) / 256), 256, 0, stream>>>(img, xbf, LI * DM / 8);
    cvt_kernel<<<dim3((LT * DM / 8 + 255) / 256), 256, 0, stream>>>(
        txt, xbf + (size_t)LI * DM, LT * DM / 8);

    gemm_qkv_a_kernel<<<dim3(60, 10), 256, 0, stream>>>(
        xbf, wbf, bq, bk, bv, bq_t, bk_t, bv_t, qraw, kraw, vraw);
    gemm_qkv_b_kernel<<<dim3(60, 9), 256, 0, stream>>>(
        xbf, wbf, bq, bk, bv, bq_t, bk_t, bv_t, qraw, kraw, vraw);

    rmsrope_kernel<<<dim3(LSEQ), 256, 0, stream>>>(
        qraw, kraw, rope, img_masks, qn, kn, qn_t, kn_t, qbf, kbf);

    transpose_cvt_kernel<<<dim3(DM / 32, LSEQ / 32), 256, 0, stream>>>(vraw, vt);

    flash_kernel<<<dim3(NH, LSEQ / 64), 256, 0, stream>>>(qbf, kbf, vt, attnbf);

    gemm_out_kernel<<<dim3(20, 19), 256, 0, stream>>>(attnbf, wbf, bo, bo_t, out);
}

// Round 5
// 600.149 us; speedup vs baseline: 1.0199x; 1.0199x over previous
//
#include <hip/hip_runtime.h>
#include <math.h>

#define LI 2048
#define LT 384
#define LSEQ 2432
#define DM 2560
#define NH 20
#define DH 128
#define SCALE 0.08838834764831845f
#define NKV 38
#define KVBUF 32768

typedef __bf16 bf16x8 __attribute__((ext_vector_type(8)));
typedef __bf16 bf16x4 __attribute__((ext_vector_type(4)));
typedef __bf16 bf16x2 __attribute__((ext_vector_type(2)));
typedef float f32x4 __attribute__((ext_vector_type(4)));

__device__ __forceinline__ void async_copy16(const void* gsrc, void* lds_uniform) {
    __builtin_amdgcn_global_load_lds(
        (const __attribute__((address_space(1))) unsigned int*)gsrc,
        (__attribute__((address_space(3))) unsigned int*)lds_uniform,
        16, 0, 0);
}

// ---------------- f32 -> bf16 conversions ----------------

__global__ __launch_bounds__(256) void cvt8_kernel(
    const float* __restrict__ s0, const float* __restrict__ s1,
    const float* __restrict__ s2, const float* __restrict__ s3,
    const float* __restrict__ s4, const float* __restrict__ s5,
    const float* __restrict__ s6, const float* __restrict__ s7,
    __bf16* __restrict__ dst)
{
    const float* srcs[8] = {s0, s1, s2, s3, s4, s5, s6, s7};
    const float* s = srcs[blockIdx.y];
    __bf16* d = dst + (size_t)blockIdx.y * (size_t)DM * DM;
    int i = blockIdx.x * 256 + threadIdx.x;
    const float4* sp = (const float4*)s + (size_t)i * 2;
    float4 a = sp[0], b = sp[1];
    bf16x8 o = {(__bf16)a.x, (__bf16)a.y, (__bf16)a.z, (__bf16)a.w,
                (__bf16)b.x, (__bf16)b.y, (__bf16)b.z, (__bf16)b.w};
    *((bf16x8*)d + i) = o;
}

__global__ __launch_bounds__(256) void cvt_kernel(
    const float* __restrict__ s, __bf16* __restrict__ d, int n8)
{
    int i = blockIdx.x * 256 + threadIdx.x;
    if (i >= n8) return;
    const float4* sp = (const float4*)s + (size_t)i * 2;
    float4 a = sp[0], b = sp[1];
    bf16x8 o = {(__bf16)a.x, (__bf16)a.y, (__bf16)a.z, (__bf16)a.w,
                (__bf16)b.x, (__bf16)b.y, (__bf16)b.z, (__bf16)b.w};
    *((bf16x8*)d + i) = o;
}

// ---------------- 128x128 bf16 GEMM core, BK=64, XOR-swizzled LDS ----------------

__device__ __forceinline__ void gemm_core(
    const __bf16* __restrict__ Ab,
    const __bf16* __restrict__ Bb,
    const float* __restrict__ bias,
    float* __restrict__ Cb,
    __bf16* sA, __bf16* sB)
{
    const int t = threadIdx.x, wave = t >> 6, lane = t & 63;
    const int l15 = lane & 15, quad = lane >> 4;
    const int wm = wave >> 1, wn = wave & 1;

    f32x4 acc[4][4];
#pragma unroll
    for (int i = 0; i < 4; i++)
#pragma unroll
        for (int j = 0; j < 4; j++) acc[i][j] = f32x4{0.f, 0.f, 0.f, 0.f};

    size_t soff[4];
#pragma unroll
    for (int j = 0; j < 4; j++) {
        int c = j * 256 + t;
        int row = c >> 3, u = c & 7;
        soff[j] = (size_t)row * DM + ((u ^ (row & 7)) * 8);
    }

    for (int k0 = 0; k0 < DM; k0 += 64) {
        __syncthreads();
#pragma unroll
        for (int j = 0; j < 4; j++)
            async_copy16(Ab + soff[j] + k0, (char*)sA + (j * 256 + wave * 64) * 16);
#pragma unroll
        for (int j = 0; j < 4; j++)
            async_copy16(Bb + soff[j] + k0, (char*)sB + (j * 256 + wave * 64) * 16);
        __syncthreads();

#pragma unroll
        for (int ks = 0; ks < 2; ks++) {
            bf16x8 af[4], bg[4];
#pragma unroll
            for (int mt = 0; mt < 4; mt++) {
                int r = wm * 64 + mt * 16 + l15;
                af[mt] = *(const bf16x8*)(sA + r * 64 + (((quad + ks * 4) ^ (r & 7)) * 8));
            }
#pragma unroll
            for (int nt = 0; nt < 4; nt++) {
                int r = wn * 64 + nt * 16 + l15;
                bg[nt] = *(const bf16x8*)(sB + r * 64 + (((quad + ks * 4) ^ (r & 7)) * 8));
            }
#pragma unroll
            for (int mt = 0; mt < 4; mt++)
#pragma unroll
                for (int nt = 0; nt < 4; nt++)
                    acc[mt][nt] = __builtin_amdgcn_mfma_f32_16x16x32_bf16(af[mt], bg[nt], acc[mt][nt], 0, 0, 0);
        }
    }

#pragma unroll
    for (int mt = 0; mt < 4; mt++) {
        const int row = wm * 64 + mt * 16 + quad * 4;
#pragma unroll
        for (int nt = 0; nt < 4; nt++) {
            const int col = wn * 64 + nt * 16 + l15;
            const float bv = bias[col];
            float* cp = Cb + (size_t)row * DM + col;
            cp[0]        = acc[mt][nt][0] + bv;
            cp[DM]       = acc[mt][nt][1] + bv;
            cp[2 * DM]   = acc[mt][nt][2] + bv;
            cp[3 * DM]   = acc[mt][nt][3] + bv;
        }
    }
}

// QKV body shared by the two split dispatches (R0 mapping: n fastest).
__device__ __forceinline__ void qkv_body(
    int nblk, int mblk,
    const __bf16* __restrict__ xbf, const __bf16* __restrict__ wbf,
    const float* __restrict__ bq, const float* __restrict__ bk, const float* __restrict__ bv,
    const float* __restrict__ bq_t, const float* __restrict__ bk_t, const float* __restrict__ bv_t,
    float* __restrict__ qraw, float* __restrict__ kraw, float* __restrict__ vraw,
    __bf16* sA, __bf16* sB)
{
    const int which = nblk / 20;               // 0=Q 1=K 2=V
    const int nloc = (nblk % 20) * 128;
    const bool is_txt = (mblk >= 16);
    const size_t WELEM = (size_t)DM * DM;
    const int widx = which + (is_txt ? 4 : 0);
    const __bf16* W = wbf + (size_t)widx * WELEM;
    const float* bias = (which == 0) ? (is_txt ? bq_t : bq)
                      : (which == 1) ? (is_txt ? bk_t : bk)
                                     : (is_txt ? bv_t : bv);
    float* C = (which == 0) ? qraw : (which == 1) ? kraw : vraw;
    gemm_core(xbf + (size_t)mblk * 128 * DM, W + (size_t)nloc * DM, bias + nloc,
              C + (size_t)mblk * 128 * DM + nloc, sA, sB);
}

__global__ __launch_bounds__(256, 4) void gemm_qkv_a_kernel(
    const __bf16* __restrict__ xbf, const __bf16* __restrict__ wbf,
    const float* __restrict__ bq, const float* __restrict__ bk, const float* __restrict__ bv,
    const float* __restrict__ bq_t, const float* __restrict__ bk_t, const float* __restrict__ bv_t,
    float* __restrict__ qraw, float* __restrict__ kraw, float* __restrict__ vraw)
{
    __shared__ alignas(16) __bf16 sA[128 * 64];
    __shared__ alignas(16) __bf16 sB[128 * 64];
    qkv_body(blockIdx.x, blockIdx.y, xbf, wbf, bq, bk, bv, bq_t, bk_t, bv_t,
             qraw, kraw, vraw, sA, sB);
}

__global__ __launch_bounds__(256, 4) void gemm_qkv_b_kernel(
    const __bf16* __restrict__ xbf, const __bf16* __restrict__ wbf,
    const float* __restrict__ bq, const float* __restrict__ bk, const float* __restrict__ bv,
    const float* __restrict__ bq_t, const float* __restrict__ bk_t, const float* __restrict__ bv_t,
    float* __restrict__ qraw, float* __restrict__ kraw, float* __restrict__ vraw)
{
    __shared__ alignas(16) __bf16 sA[128 * 64];
    __shared__ alignas(16) __bf16 sB[128 * 64];
    qkv_body(blockIdx.x, blockIdx.y + 10, xbf, wbf, bq, bk, bv, bq_t, bk_t, bv_t,
             qraw, kraw, vraw, sA, sB);
}

// Out-proj: grid (20, 19), R0 mapping.
__global__ __launch_bounds__(256, 4) void gemm_out_kernel(
    const __bf16* __restrict__ attnbf, const __bf16* __restrict__ wbf,
    const float* __restrict__ bo, const float* __restrict__ bo_t,
    float* __restrict__ out)
{
    __shared__ alignas(16) __bf16 sA[128 * 64];
    __shared__ alignas(16) __bf16 sB[128 * 64];
    const int nblk = blockIdx.x, mblk = blockIdx.y;
    const bool is_txt = (mblk >= 16);
    const size_t WELEM = (size_t)DM * DM;
    const __bf16* W = wbf + (size_t)(is_txt ? 7 : 3) * WELEM;
    const float* bias = (is_txt ? bo_t : bo) + nblk * 128;
    gemm_core(attnbf + (size_t)mblk * 128 * DM, W + (size_t)nblk * 128 * DM, bias,
              out + (size_t)mblk * 128 * DM + nblk * 128, sA, sB);
}

// ---------------- RMS norm + qn/kn + mask + RoPE, f32 -> bf16 ----------------

__global__ __launch_bounds__(256) void rmsrope_kernel(
    const float* __restrict__ qraw, const float* __restrict__ kraw,
    const float* __restrict__ rope, const float* __restrict__ img_masks,
    const float* __restrict__ qn, const float* __restrict__ kn,
    const float* __restrict__ qn_t, const float* __restrict__ kn_t,
    __bf16* __restrict__ qbf, __bf16* __restrict__ kbf)
{
    const int l = blockIdx.x, t = threadIdx.x;
    const int wave = t >> 6, lane = t & 63;
    const bool is_img = (l < LI);
    const float* qw = is_img ? qn : qn_t;
    const float* kw = is_img ? kn : kn_t;
    const float kmask = is_img ? img_masks[l] : 1.0f;
    const float* qr = qraw + (size_t)l * DM;
    const float* kr = kraw + (size_t)l * DM;

    float2 qv[5], kv[5];
    float sq = 0.f, sk = 0.f;
#pragma unroll
    for (int j = 0; j < 5; j++) {
        int c2 = j * 256 + t;
        qv[j] = *(const float2*)(qr + 2 * c2);
        kv[j] = *(const float2*)(kr + 2 * c2);
        sq += qv[j].x * qv[j].x + qv[j].y * qv[j].y;
        sk += kv[j].x * kv[j].x + kv[j].y * kv[j].y;
    }
#pragma unroll
    for (int m = 32; m; m >>= 1) { sq += __shfl_xor(sq, m); sk += __shfl_xor(sk, m); }
    __shared__ float redq[4], redk[4];
    if (lane == 0) { redq[wave] = sq; redk[wave] = sk; }
    __syncthreads();
    sq = redq[0] + redq[1] + redq[2] + redq[3];
    sk = redk[0] + redk[1] + redk[2] + redk[3];
    const float rq = rsqrtf(sq * (1.0f / DM) + 1e-5f);
    const float rk = rsqrtf(sk * (1.0f / DM) + 1e-5f) * kmask;

#pragma unroll
    for (int j = 0; j < 5; j++) {
        int c2 = j * 256 + t;
        int c = 2 * c2;
        float4 rp = *(const float4*)(rope + ((size_t)l * 64 + (c2 & 63)) * 4);
        float2 w2q = *(const float2*)(qw + c);
        float2 w2k = *(const float2*)(kw + c);
        float x0 = qv[j].x * rq * w2q.x, x1 = qv[j].y * rq * w2q.y;
        bf16x2 oq = {(__bf16)(rp.x * x0 + rp.y * x1), (__bf16)(rp.z * x0 + rp.w * x1)};
        *(bf16x2*)(qbf + (size_t)l * DM + c) = oq;
        float y0 = kv[j].x * rk * w2k.x, y1 = kv[j].y * rk * w2k.y;
        bf16x2 ok = {(__bf16)(rp.x * y0 + rp.y * y1), (__bf16)(rp.z * y0 + rp.w * y1)};
        *(bf16x2*)(kbf + (size_t)l * DM + c) = ok;
    }
}

// ---------------- transpose V (L,DM) f32 -> (DM,L) bf16 ----------------

__global__ __launch_bounds__(256) void transpose_cvt_kernel(
    const float* __restrict__ src, __bf16* __restrict__ dst)
{
    __shared__ float tile[32][33];
    const int c0 = blockIdx.x * 32;
    const int r0 = blockIdx.y * 32;
    const int tc = threadIdx.x & 31, tr = threadIdx.x >> 5;
#pragma unroll
    for (int j = 0; j < 4; j++)
        tile[tr + j * 8][tc] = src[(size_t)(r0 + tr + j * 8) * DM + c0 + tc];
    __syncthreads();
#pragma unroll
    for (int j = 0; j < 4; j++)
        dst[(size_t)(c0 + tr + j * 8) * LSEQ + r0 + tc] = (__bf16)tile[tc][tr + j * 8];
}

// ---------------- flash attention v2 ----------------
// 4 waves x 32 q-rows (2 subtiles of 16 sharing every K/V fragment read ->
// reads/MFMA 0.56:1 vs 1:1), K/V double-buffered via global_load_lds with
// counted vmcnt(8) (stage tau+1 under compute of tau; never drain mid-loop).
// LDS: [buf0 K16K|V16K][buf1 K16K|V16K][sP 16K] = 80 KiB -> 2 blocks/CU.
// grid (20 heads, 19 qtiles of 128): 380 blocks, all co-resident.

__global__ __launch_bounds__(256, 2) void flash_kernel(
    const __bf16* __restrict__ qb, const __bf16* __restrict__ kb,
    const __bf16* __restrict__ vt, __bf16* __restrict__ ob)
{
    extern __shared__ __align__(16) char smem[];   // 81920
    const int head = blockIdx.x;
    const int q0 = blockIdx.y * 128;
    const int t = threadIdx.x, wave = t >> 6, lane = t & 63;
    const int l15 = lane & 15, quad = lane >> 4;

    bf16x8 aq[2][4];
#pragma unroll
    for (int s = 0; s < 2; s++)
#pragma unroll
        for (int d = 0; d < 4; d++)
            aq[s][d] = *(const bf16x8*)(qb + (size_t)(q0 + wave * 32 + s * 16 + l15) * DM
                                        + head * DH + d * 32 + quad * 8);

    // staging source offsets (swizzle pre-inverted); unit c = j*256 + t
    int koff[4], voff[4];
#pragma unroll
    for (int j = 0; j < 4; j++) {
        int c = j * 256 + t;
        int krow = c >> 4, ku = (c & 15) ^ (krow & 7);
        koff[j] = krow * DM + head * DH + ku * 8;
        int vrow = c >> 3, vu = (c & 7) ^ (vrow & 7);
        voff[j] = (head * DH + vrow) * LSEQ + vu * 8;
    }
    // LDS dest uniform bases (HW adds lane*16)
    const int dunit = wave * 64 * 16;

    f32x4 o0[8], o1[8];
#pragma unroll
    for (int i = 0; i < 8; i++) { o0[i] = f32x4{0.f,0.f,0.f,0.f}; o1[i] = f32x4{0.f,0.f,0.f,0.f}; }
    float m0 = -INFINITY, m1 = -INFINITY, li0 = 0.f, li1 = 0.f;
    __bf16* pw0 = (__bf16*)(smem + 2 * KVBUF) + (wave * 2 + 0) * (16 * 64);
    __bf16* pw1 = (__bf16*)(smem + 2 * KVBUF) + (wave * 2 + 1) * (16 * 64);

    // prologue: stage tile 0 -> buf0 (8 loads/thread in flight)
#pragma unroll
    for (int j = 0; j < 4; j++) {
        async_copy16(kb + koff[j], smem + j * 4096 + dunit);
        async_copy16(vt + voff[j], smem + 16384 + j * 4096 + dunit);
    }

    for (int it = 0; it < NKV; ++it) {
        const int kv0 = it * 64;
        char* cur = smem + (it & 1) * KVBUF;
        char* nxt = smem + ((it + 1) & 1) * KVBUF;
        if (it + 1 < NKV) {
#pragma unroll
            for (int j = 0; j < 4; j++) {
                async_copy16(kb + koff[j] + (size_t)(kv0 + 64) * DM, nxt + j * 4096 + dunit);
                async_copy16(vt + voff[j] + (kv0 + 64), nxt + 16384 + j * 4096 + dunit);
            }
            asm volatile("s_waitcnt vmcnt(8)" ::: "memory");  // tile it landed; it+1 in flight
        } else {
            asm volatile("s_waitcnt vmcnt(0)" ::: "memory");
        }
        __builtin_amdgcn_s_barrier();
        __builtin_amdgcn_sched_barrier(0);
        const __bf16* sK = (const __bf16*)cur;
        const __bf16* sV = (const __bf16*)(cur + 16384);

        f32x4 st0[4], st1[4];
        __builtin_amdgcn_s_setprio(1);
#pragma unroll
        for (int b = 0; b < 4; b++) {
            st0[b] = f32x4{0.f,0.f,0.f,0.f};
            st1[b] = f32x4{0.f,0.f,0.f,0.f};
#pragma unroll
            for (int d = 0; d < 4; d++) {
                int row = b * 16 + l15;
                bf16x8 ak = *(const bf16x8*)(sK + row * 128 + (((d * 4 + quad) ^ (row & 7)) * 8));
                st0[b] = __builtin_amdgcn_mfma_f32_16x16x32_bf16(ak, aq[0][d], st0[b], 0, 0, 0);
                st1[b] = __builtin_amdgcn_mfma_f32_16x16x32_bf16(ak, aq[1][d], st1[b], 0, 0, 0);
            }
        }
        __builtin_amdgcn_s_setprio(0);

        float mx0 = m0, mx1 = m1;
#pragma unroll
        for (int b = 0; b < 4; b++)
#pragma unroll
            for (int r = 0; r < 4; r++) {
                st0[b][r] *= SCALE; mx0 = fmaxf(mx0, st0[b][r]);
                st1[b][r] *= SCALE; mx1 = fmaxf(mx1, st1[b][r]);
            }
        mx0 = fmaxf(mx0, __shfl_xor(mx0, 16)); mx0 = fmaxf(mx0, __shfl_xor(mx0, 32));
        mx1 = fmaxf(mx1, __shfl_xor(mx1, 16)); mx1 = fmaxf(mx1, __shfl_xor(mx1, 32));
        const float al0 = __expf(m0 - mx0); m0 = mx0;
        const float al1 = __expf(m1 - mx1); m1 = mx1;
        float sum0 = 0.f, sum1 = 0.f;
#pragma unroll
        for (int b = 0; b < 4; b++)
#pragma unroll
            for (int r = 0; r < 4; r++) {
                float p0 = __expf(st0[b][r] - mx0); st0[b][r] = p0; sum0 += p0;
                float p1 = __expf(st1[b][r] - mx1); st1[b][r] = p1; sum1 += p1;
            }
        sum0 += __shfl_xor(sum0, 16); sum0 += __shfl_xor(sum0, 32);
        sum1 += __shfl_xor(sum1, 16); sum1 += __shfl_xor(sum1, 32);
        li0 = li0 * al0 + sum0;
        li1 = li1 * al1 + sum1;

#pragma unroll
        for (int b = 0; b < 4; b++) {
            int u = 2 * b + (quad >> 1);
            bf16x4 pk0 = {(__bf16)st0[b][0], (__bf16)st0[b][1], (__bf16)st0[b][2], (__bf16)st0[b][3]};
            *(bf16x4*)(pw0 + l15 * 64 + ((u ^ (l15 & 7)) * 8) + (quad & 1) * 4) = pk0;
            bf16x4 pk1 = {(__bf16)st1[b][0], (__bf16)st1[b][1], (__bf16)st1[b][2], (__bf16)st1[b][3]};
            *(bf16x4*)(pw1 + l15 * 64 + ((u ^ (l15 & 7)) * 8) + (quad & 1) * 4) = pk1;
        }

        float alr0[4], alr1[4];
#pragma unroll
        for (int r = 0; r < 4; r++) {
            alr0[r] = __shfl(al0, quad * 4 + r);
            alr1[r] = __shfl(al1, quad * 4 + r);
        }
#pragma unroll
        for (int i = 0; i < 8; i++) {
            f32x4 t0 = o0[i], t1 = o1[i];
            t0[0] *= alr0[0]; t0[1] *= alr0[1]; t0[2] *= alr0[2]; t0[3] *= alr0[3];
            t1[0] *= alr1[0]; t1[1] *= alr1[1]; t1[2] *= alr1[2]; t1[3] *= alr1[3];
            o0[i] = t0; o1[i] = t1;
        }
        __asm__ volatile("s_waitcnt lgkmcnt(0)" ::: "memory");

        bf16x8 ap00 = *(const bf16x8*)(pw0 + l15 * 64 + ((quad ^ (l15 & 7)) * 8));
        bf16x8 ap01 = *(const bf16x8*)(pw0 + l15 * 64 + (((4 + quad) ^ (l15 & 7)) * 8));
        bf16x8 ap10 = *(const bf16x8*)(pw1 + l15 * 64 + ((quad ^ (l15 & 7)) * 8));
        bf16x8 ap11 = *(const bf16x8*)(pw1 + l15 * 64 + (((4 + quad) ^ (l15 & 7)) * 8));
        __builtin_amdgcn_s_setprio(1);
#pragma unroll
        for (int n2 = 0; n2 < 8; n2++) {
            int row = n2 * 16 + l15;
            bf16x8 bv0 = *(const bf16x8*)(sV + row * 64 + ((quad ^ (row & 7)) * 8));
            bf16x8 bv1 = *(const bf16x8*)(sV + row * 64 + (((4 + quad) ^ (row & 7)) * 8));
            o0[n2] = __builtin_amdgcn_mfma_f32_16x16x32_bf16(ap00, bv0, o0[n2], 0, 0, 0);
            o0[n2] = __builtin_amdgcn_mfma_f32_16x16x32_bf16(ap01, bv1, o0[n2], 0, 0, 0);
            o1[n2] = __builtin_amdgcn_mfma_f32_16x16x32_bf16(ap10, bv0, o1[n2], 0, 0, 0);
            o1[n2] = __builtin_amdgcn_mfma_f32_16x16x32_bf16(ap11, bv1, o1[n2], 0, 0, 0);
        }
        __builtin_amdgcn_s_setprio(0);
        __builtin_amdgcn_s_barrier();   // all reads of cur done before it is restaged
    }

    const float inv0 = 1.0f / li0, inv1 = 1.0f / li1;
    float ivr0[4], ivr1[4];
#pragma unroll
    for (int r = 0; r < 4; r++) {
        ivr0[r] = __shfl(inv0, quad * 4 + r);
        ivr1[r] = __shfl(inv1, quad * 4 + r);
    }
#pragma unroll
    for (int n2 = 0; n2 < 8; n2++)
#pragma unroll
        for (int r = 0; r < 4; r++) {
            ob[(size_t)(q0 + wave * 32 + quad * 4 + r) * DM + head * DH + n2 * 16 + l15] =
                (__bf16)(o0[n2][r] * ivr0[r]);
            ob[(size_t)(q0 + wave * 32 + 16 + quad * 4 + r) * DM + head * DH + n2 * 16 + l15] =
                (__bf16)(o1[n2][r] * ivr1[r]);
        }
}

// ---------------- launch ----------------

extern "C" void kernel_launch(void* const* d_in, const int* in_sizes, int n_in,
                              void* d_out, int out_size, void* d_ws, size_t ws_size,
                              hipStream_t stream) {
    const float* img       = (const float*)d_in[0];
    const float* txt       = (const float*)d_in[1];
    const float* rope      = (const float*)d_in[2];
    const float* img_masks = (const float*)d_in[3];
    const float* Wq   = (const float*)d_in[4];  const float* bq   = (const float*)d_in[5];
    const float* Wk   = (const float*)d_in[6];  const float* bk   = (const float*)d_in[7];
    const float* Wv   = (const float*)d_in[8];  const float* bv   = (const float*)d_in[9];
    const float* Wo   = (const float*)d_in[10]; const float* bo   = (const float*)d_in[11];
    const float* Wq_t = (const float*)d_in[12]; const float* bq_t = (const float*)d_in[13];
    const float* Wk_t = (const float*)d_in[14]; const float* bk_t = (const float*)d_in[15];
    const float* Wv_t = (const float*)d_in[16]; const float* bv_t = (const float*)d_in[17];
    const float* Wo_t = (const float*)d_in[18]; const float* bo_t = (const float*)d_in[19];
    const float* qn   = (const float*)d_in[20]; const float* kn   = (const float*)d_in[21];
    const float* qn_t = (const float*)d_in[22]; const float* kn_t = (const float*)d_in[23];
    float* out = (float*)d_out;

    static bool inited = false;
    if (!inited) {
        hipFuncSetAttribute(reinterpret_cast<const void*>(flash_kernel),
                            hipFuncAttributeMaxDynamicSharedMemorySize, 81920);
        inited = true;
    }

    const size_t WELEM = (size_t)DM * DM;
    const size_t XELEM = (size_t)LSEQ * DM;

    __bf16* wbf  = (__bf16*)d_ws;
    __bf16* xbf  = wbf + 8 * WELEM;
    float*  qraw = (float*)(xbf + XELEM);
    float*  kraw = qraw + XELEM;
    float*  vraw = kraw + XELEM;
    __bf16* qbf  = (__bf16*)(vraw + XELEM);
    __bf16* kbf  = qbf + XELEM;
    __bf16* vt   = kbf + XELEM;
    __bf16* attnbf = (__bf16*)qraw;                // reuse (qraw dead after rmsrope)

    cvt8_kernel<<<dim3((int)(WELEM / 8 / 256), 8), 256, 0, stream>>>(
        Wq, Wk, Wv, Wo, Wq_t, Wk_t, Wv_t, Wo_t, wbf);
    cvt_kernel<<<dim3((LI * DM / 8 + 255) / 256), 256, 0, stream>>>(img, xbf, LI * DM / 8);
    cvt_kernel<<<dim3((LT * DM / 8 + 255) / 256), 256, 0, stream>>>(
        txt, xbf + (size_t)LI * DM, LT * DM / 8);

    gemm_qkv_a_kernel<<<dim3(60, 10), 256, 0, stream>>>(
        xbf, wbf, bq, bk, bv, bq_t, bk_t, bv_t, qraw, kraw, vraw);
    gemm_qkv_b_kernel<<<dim3(60, 9), 256, 0, stream>>>(
        xbf, wbf, bq, bk, bv, bq_t, bk_t, bv_t, qraw, kraw, vraw);

    rmsrope_kernel<<<dim3(LSEQ), 256, 0, stream>>>(
        qraw, kraw, rope, img_masks, qn, kn, qn_t, kn_t, qbf, kbf);

    transpose_cvt_kernel<<<dim3(DM / 32, LSEQ / 32), 256, 0, stream>>>(vraw, vt);

    flash_kernel<<<dim3(NH, LSEQ / 128), 256, 81920, stream>>>(qbf, kbf, vt, attnbf);

    gemm_out_kernel<<<dim3(20, 19), 256, 0, stream>>>(attnbf, wbf, bo, bo_t, out);
}

// Round 6
// 583.745 us; speedup vs baseline: 1.0486x; 1.0281x over previous
//
#include <hip/hip_runtime.h>
#include <math.h>

#define LI 2048
#define LT 384
#define LSEQ 2432
#define DM 2560
#define NH 20
#define DH 128
#define SCALE 0.08838834764831845f
#define NKV 38

typedef __bf16 bf16x8 __attribute__((ext_vector_type(8)));
typedef __bf16 bf16x4 __attribute__((ext_vector_type(4)));
typedef __bf16 bf16x2 __attribute__((ext_vector_type(2)));
typedef float f32x4 __attribute__((ext_vector_type(4)));
typedef float f32x16 __attribute__((ext_vector_type(16)));

__device__ __forceinline__ void async_copy16(const void* gsrc, void* lds_uniform) {
    __builtin_amdgcn_global_load_lds(
        (const __attribute__((address_space(1))) unsigned int*)gsrc,
        (__attribute__((address_space(3))) unsigned int*)lds_uniform,
        16, 0, 0);
}

// ---------------- f32 -> bf16 conversions ----------------

__global__ __launch_bounds__(256) void cvt8_kernel(
    const float* __restrict__ s0, const float* __restrict__ s1,
    const float* __restrict__ s2, const float* __restrict__ s3,
    const float* __restrict__ s4, const float* __restrict__ s5,
    const float* __restrict__ s6, const float* __restrict__ s7,
    __bf16* __restrict__ dst)
{
    const float* srcs[8] = {s0, s1, s2, s3, s4, s5, s6, s7};
    const float* s = srcs[blockIdx.y];
    __bf16* d = dst + (size_t)blockIdx.y * (size_t)DM * DM;
    int i = blockIdx.x * 256 + threadIdx.x;
    const float4* sp = (const float4*)s + (size_t)i * 2;
    float4 a = sp[0], b = sp[1];
    bf16x8 o = {(__bf16)a.x, (__bf16)a.y, (__bf16)a.z, (__bf16)a.w,
                (__bf16)b.x, (__bf16)b.y, (__bf16)b.z, (__bf16)b.w};
    *((bf16x8*)d + i) = o;
}

__global__ __launch_bounds__(256) void cvt_kernel(
    const float* __restrict__ s, __bf16* __restrict__ d, int n8)
{
    int i = blockIdx.x * 256 + threadIdx.x;
    if (i >= n8) return;
    const float4* sp = (const float4*)s + (size_t)i * 2;
    float4 a = sp[0], b = sp[1];
    bf16x8 o = {(__bf16)a.x, (__bf16)a.y, (__bf16)a.z, (__bf16)a.w,
                (__bf16)b.x, (__bf16)b.y, (__bf16)b.z, (__bf16)b.w};
    *((bf16x8*)d + i) = o;
}

// ---------------- 128x128 bf16 GEMM core, BK=64, XOR-swizzled LDS ----------------

__device__ __forceinline__ void gemm_core(
    const __bf16* __restrict__ Ab,
    const __bf16* __restrict__ Bb,
    const float* __restrict__ bias,
    float* __restrict__ Cb,
    __bf16* sA, __bf16* sB)
{
    const int t = threadIdx.x, wave = t >> 6, lane = t & 63;
    const int l15 = lane & 15, quad = lane >> 4;
    const int wm = wave >> 1, wn = wave & 1;

    f32x4 acc[4][4];
#pragma unroll
    for (int i = 0; i < 4; i++)
#pragma unroll
        for (int j = 0; j < 4; j++) acc[i][j] = f32x4{0.f, 0.f, 0.f, 0.f};

    size_t soff[4];
#pragma unroll
    for (int j = 0; j < 4; j++) {
        int c = j * 256 + t;
        int row = c >> 3, u = c & 7;
        soff[j] = (size_t)row * DM + ((u ^ (row & 7)) * 8);
    }

    for (int k0 = 0; k0 < DM; k0 += 64) {
        __syncthreads();
#pragma unroll
        for (int j = 0; j < 4; j++)
            async_copy16(Ab + soff[j] + k0, (char*)sA + (j * 256 + wave * 64) * 16);
#pragma unroll
        for (int j = 0; j < 4; j++)
            async_copy16(Bb + soff[j] + k0, (char*)sB + (j * 256 + wave * 64) * 16);
        __syncthreads();

#pragma unroll
        for (int ks = 0; ks < 2; ks++) {
            bf16x8 af[4], bg[4];
#pragma unroll
            for (int mt = 0; mt < 4; mt++) {
                int r = wm * 64 + mt * 16 + l15;
                af[mt] = *(const bf16x8*)(sA + r * 64 + (((quad + ks * 4) ^ (r & 7)) * 8));
            }
#pragma unroll
            for (int nt = 0; nt < 4; nt++) {
                int r = wn * 64 + nt * 16 + l15;
                bg[nt] = *(const bf16x8*)(sB + r * 64 + (((quad + ks * 4) ^ (r & 7)) * 8));
            }
#pragma unroll
            for (int mt = 0; mt < 4; mt++)
#pragma unroll
                for (int nt = 0; nt < 4; nt++)
                    acc[mt][nt] = __builtin_amdgcn_mfma_f32_16x16x32_bf16(af[mt], bg[nt], acc[mt][nt], 0, 0, 0);
        }
    }

#pragma unroll
    for (int mt = 0; mt < 4; mt++) {
        const int row = wm * 64 + mt * 16 + quad * 4;
#pragma unroll
        for (int nt = 0; nt < 4; nt++) {
            const int col = wn * 64 + nt * 16 + l15;
            const float bv = bias[col];
            float* cp = Cb + (size_t)row * DM + col;
            cp[0]        = acc[mt][nt][0] + bv;
            cp[DM]       = acc[mt][nt][1] + bv;
            cp[2 * DM]   = acc[mt][nt][2] + bv;
            cp[3 * DM]   = acc[mt][nt][3] + bv;
        }
    }
}

// QKV body shared by the two split dispatches (R0 mapping: n fastest).
__device__ __forceinline__ void qkv_body(
    int nblk, int mblk,
    const __bf16* __restrict__ xbf, const __bf16* __restrict__ wbf,
    const float* __restrict__ bq, const float* __restrict__ bk, const float* __restrict__ bv,
    const float* __restrict__ bq_t, const float* __restrict__ bk_t, const float* __restrict__ bv_t,
    float* __restrict__ qraw, float* __restrict__ kraw, float* __restrict__ vraw,
    __bf16* sA, __bf16* sB)
{
    const int which = nblk / 20;               // 0=Q 1=K 2=V
    const int nloc = (nblk % 20) * 128;
    const bool is_txt = (mblk >= 16);
    const size_t WELEM = (size_t)DM * DM;
    const int widx = which + (is_txt ? 4 : 0);
    const __bf16* W = wbf + (size_t)widx * WELEM;
    const float* bias = (which == 0) ? (is_txt ? bq_t : bq)
                      : (which == 1) ? (is_txt ? bk_t : bk)
                                     : (is_txt ? bv_t : bv);
    float* C = (which == 0) ? qraw : (which == 1) ? kraw : vraw;
    gemm_core(xbf + (size_t)mblk * 128 * DM, W + (size_t)nloc * DM, bias + nloc,
              C + (size_t)mblk * 128 * DM + nloc, sA, sB);
}

__global__ __launch_bounds__(256, 4) void gemm_qkv_a_kernel(
    const __bf16* __restrict__ xbf, const __bf16* __restrict__ wbf,
    const float* __restrict__ bq, const float* __restrict__ bk, const float* __restrict__ bv,
    const float* __restrict__ bq_t, const float* __restrict__ bk_t, const float* __restrict__ bv_t,
    float* __restrict__ qraw, float* __restrict__ kraw, float* __restrict__ vraw)
{
    __shared__ alignas(16) __bf16 sA[128 * 64];
    __shared__ alignas(16) __bf16 sB[128 * 64];
    qkv_body(blockIdx.x, blockIdx.y, xbf, wbf, bq, bk, bv, bq_t, bk_t, bv_t,
             qraw, kraw, vraw, sA, sB);
}

__global__ __launch_bounds__(256, 4) void gemm_qkv_b_kernel(
    const __bf16* __restrict__ xbf, const __bf16* __restrict__ wbf,
    const float* __restrict__ bq, const float* __restrict__ bk, const float* __restrict__ bv,
    const float* __restrict__ bq_t, const float* __restrict__ bk_t, const float* __restrict__ bv_t,
    float* __restrict__ qraw, float* __restrict__ kraw, float* __restrict__ vraw)
{
    __shared__ alignas(16) __bf16 sA[128 * 64];
    __shared__ alignas(16) __bf16 sB[128 * 64];
    qkv_body(blockIdx.x, blockIdx.y + 10, xbf, wbf, bq, bk, bv, bq_t, bk_t, bv_t,
             qraw, kraw, vraw, sA, sB);
}

// Out-proj: grid (20, 19), R0 mapping.
__global__ __launch_bounds__(256, 4) void gemm_out_kernel(
    const __bf16* __restrict__ attnbf, const __bf16* __restrict__ wbf,
    const float* __restrict__ bo, const float* __restrict__ bo_t,
    float* __restrict__ out)
{
    __shared__ alignas(16) __bf16 sA[128 * 64];
    __shared__ alignas(16) __bf16 sB[128 * 64];
    const int nblk = blockIdx.x, mblk = blockIdx.y;
    const bool is_txt = (mblk >= 16);
    const size_t WELEM = (size_t)DM * DM;
    const __bf16* W = wbf + (size_t)(is_txt ? 7 : 3) * WELEM;
    const float* bias = (is_txt ? bo_t : bo) + nblk * 128;
    gemm_core(attnbf + (size_t)mblk * 128 * DM, W + (size_t)nblk * 128 * DM, bias,
              out + (size_t)mblk * 128 * DM + nblk * 128, sA, sB);
}

// ---------------- RMS norm + qn/kn + mask + RoPE, f32 -> bf16 ----------------

__global__ __launch_bounds__(256) void rmsrope_kernel(
    const float* __restrict__ qraw, const float* __restrict__ kraw,
    const float* __restrict__ rope, const float* __restrict__ img_masks,
    const float* __restrict__ qn, const float* __restrict__ kn,
    const float* __restrict__ qn_t, const float* __restrict__ kn_t,
    __bf16* __restrict__ qbf, __bf16* __restrict__ kbf)
{
    const int l = blockIdx.x, t = threadIdx.x;
    const int wave = t >> 6, lane = t & 63;
    const bool is_img = (l < LI);
    const float* qw = is_img ? qn : qn_t;
    const float* kw = is_img ? kn : kn_t;
    const float kmask = is_img ? img_masks[l] : 1.0f;
    const float* qr = qraw + (size_t)l * DM;
    const float* kr = kraw + (size_t)l * DM;

    float2 qv[5], kv[5];
    float sq = 0.f, sk = 0.f;
#pragma unroll
    for (int j = 0; j < 5; j++) {
        int c2 = j * 256 + t;
        qv[j] = *(const float2*)(qr + 2 * c2);
        kv[j] = *(const float2*)(kr + 2 * c2);
        sq += qv[j].x * qv[j].x + qv[j].y * qv[j].y;
        sk += kv[j].x * kv[j].x + kv[j].y * kv[j].y;
    }
#pragma unroll
    for (int m = 32; m; m >>= 1) { sq += __shfl_xor(sq, m); sk += __shfl_xor(sk, m); }
    __shared__ float redq[4], redk[4];
    if (lane == 0) { redq[wave] = sq; redk[wave] = sk; }
    __syncthreads();
    sq = redq[0] + redq[1] + redq[2] + redq[3];
    sk = redk[0] + redk[1] + redk[2] + redk[3];
    const float rq = rsqrtf(sq * (1.0f / DM) + 1e-5f);
    const float rk = rsqrtf(sk * (1.0f / DM) + 1e-5f) * kmask;

#pragma unroll
    for (int j = 0; j < 5; j++) {
        int c2 = j * 256 + t;
        int c = 2 * c2;
        float4 rp = *(const float4*)(rope + ((size_t)l * 64 + (c2 & 63)) * 4);
        float2 w2q = *(const float2*)(qw + c);
        float2 w2k = *(const float2*)(kw + c);
        float x0 = qv[j].x * rq * w2q.x, x1 = qv[j].y * rq * w2q.y;
        bf16x2 oq = {(__bf16)(rp.x * x0 + rp.y * x1), (__bf16)(rp.z * x0 + rp.w * x1)};
        *(bf16x2*)(qbf + (size_t)l * DM + c) = oq;
        float y0 = kv[j].x * rk * w2k.x, y1 = kv[j].y * rk * w2k.y;
        bf16x2 ok = {(__bf16)(rp.x * y0 + rp.y * y1), (__bf16)(rp.z * y0 + rp.w * y1)};
        *(bf16x2*)(kbf + (size_t)l * DM + c) = ok;
    }
}

// ---------------- transpose V (L,DM) f32 -> (DM,L) bf16 ----------------

__global__ __launch_bounds__(256) void transpose_cvt_kernel(
    const float* __restrict__ src, __bf16* __restrict__ dst)
{
    __shared__ float tile[32][33];
    const int c0 = blockIdx.x * 32;
    const int r0 = blockIdx.y * 32;
    const int tc = threadIdx.x & 31, tr = threadIdx.x >> 5;
#pragma unroll
    for (int j = 0; j < 4; j++)
        tile[tr + j * 8][tc] = src[(size_t)(r0 + tr + j * 8) * DM + c0 + tc];
    __syncthreads();
#pragma unroll
    for (int j = 0; j < 4; j++)
        dst[(size_t)(c0 + tr + j * 8) * LSEQ + r0 + tc] = (__bf16)tile[tc][tr + j * 8];
}

// ---------------- flash attention v3: 32x32 MFMA + kv-split ----------------
// block = 4 waves = 2 q-subtiles (s) x 2 kv-halves (h); QBLK=64 -> grid (20,38),
// 760 blocks x 4 = 3040 waves (full TLP). Per wave-iter: 16 MFMA 32x32x16 with
// only 16 b128 LDS reads (vs 34 in 16x16 form). QK^T: S[kv][q], q=lane&31 ->
// softmax lane-local; P assembled IN-REGISTER (8 cvt-pk + 8 shfl_xor32, no sP).
// PV as mfma(A=V, B=P) -> O has q=lane (rescale broadcast-free). kv-halves
// merged once per block via LDS (log-sum-exp merge).
// LDS: sK 16K + sV 16K (main loop); obuf 2x16896 + mlbuf 1K (merge, aliased).

__global__ __launch_bounds__(256, 3) void flash_kernel(
    const __bf16* __restrict__ qb, const __bf16* __restrict__ kb,
    const __bf16* __restrict__ vt, __bf16* __restrict__ ob)
{
    __shared__ alignas(16) char smem[34816];
    const int head = blockIdx.x;
    const int q0 = blockIdx.y * 64;
    const int t = threadIdx.x, wave = t >> 6, lane = t & 63;
    const int s = wave >> 1, h = wave & 1;
    const int l31 = lane & 31, h5 = lane >> 5;

    // Q fragments (B-operand, 32x32x16): lane: row=q=l31, k = 16*t8 + 8*h5 + 0..7
    bf16x8 bq8[8];
    {
        const __bf16* qp = qb + (size_t)(q0 + s * 32 + l31) * DM + head * DH;
#pragma unroll
        for (int t8 = 0; t8 < 8; t8++)
            bq8[t8] = *(const bf16x8*)(qp + t8 * 16 + h5 * 8);
    }

    // staging source offsets (identical to verified R5 layout/swizzle)
    int koff[4], voff[4];
#pragma unroll
    for (int j = 0; j < 4; j++) {
        int c = j * 256 + t;
        int krow = c >> 4, ku = (c & 15) ^ (krow & 7);
        koff[j] = krow * DM + head * DH + ku * 8;
        int vrow = c >> 3, vu = (c & 7) ^ (vrow & 7);
        voff[j] = (head * DH + vrow) * LSEQ + vu * 8;
    }
    const int dunit = wave * 1024;          // HW adds lane*16

    const __bf16* sK = (const __bf16*)smem;
    const __bf16* sV = (const __bf16*)(smem + 16384);
    const int kbase = 32 * h;               // wave's kv-half within the 64-tile

    f32x16 o[4];
#pragma unroll
    for (int dt = 0; dt < 4; dt++)
#pragma unroll
        for (int e = 0; e < 16; e++) o[dt][e] = 0.f;
    float m_i = -INFINITY, l_i = 0.f;

    for (int it = 0; it < NKV; ++it) {
        __syncthreads();                      // prev iter LDS reads done
#pragma unroll
        for (int j = 0; j < 4; j++) {
            async_copy16(kb + koff[j] + (size_t)(it * 64) * DM, smem + j * 4096 + dunit);
            async_copy16(vt + voff[j] + it * 64, smem + 16384 + j * 4096 + dunit);
        }
        __syncthreads();                      // vmcnt drained -> tile staged

        // ---- QK^T: st[kv(reg)][q(lane)] over this wave's 32-kv half
        f32x16 st;
#pragma unroll
        for (int e = 0; e < 16; e++) st[e] = 0.f;
        __builtin_amdgcn_s_setprio(1);
#pragma unroll
        for (int t8 = 0; t8 < 8; t8++) {
            int row = kbase + l31;
            int unit = (2 * t8 + h5) ^ (row & 7);
            bf16x8 ak = *(const bf16x8*)(sK + row * 128 + unit * 8);
            st = __builtin_amdgcn_mfma_f32_32x32x16_bf16(ak, bq8[t8], st, 0, 0, 0);
        }
        __builtin_amdgcn_s_setprio(0);

        // ---- softmax (q lane-local; reduce over 16 regs + lane^32 partner)
        float mx = m_i;
#pragma unroll
        for (int e = 0; e < 16; e++) { st[e] *= SCALE; mx = fmaxf(mx, st[e]); }
        mx = fmaxf(mx, __shfl_xor(mx, 32));
        const float al = __expf(m_i - mx);
        m_i = mx;
        float sum = 0.f;
#pragma unroll
        for (int e = 0; e < 16; e++) { float p = __expf(st[e] - mx); st[e] = p; sum += p; }
        sum += __shfl_xor(sum, 32);
        l_i = l_i * al + sum;
#pragma unroll
        for (int dt = 0; dt < 4; dt++)
#pragma unroll
            for (int e = 0; e < 16; e++) o[dt][e] *= al;

        // ---- P fragments in-register (k ascending per chunk of 16 kv)
        bf16x8 pfrag[2];
#pragma unroll
        for (int c = 0; c < 2; c++) {
            union { bf16x2 v; unsigned u; } A, B, C, D;
            A.v = bf16x2{(__bf16)st[8 * c + 0], (__bf16)st[8 * c + 1]};
            B.v = bf16x2{(__bf16)st[8 * c + 2], (__bf16)st[8 * c + 3]};
            C.v = bf16x2{(__bf16)st[8 * c + 4], (__bf16)st[8 * c + 5]};
            D.v = bf16x2{(__bf16)st[8 * c + 6], (__bf16)st[8 * c + 7]};
            unsigned xA = __shfl_xor(A.u, 32), xB = __shfl_xor(B.u, 32);
            unsigned xC = __shfl_xor(C.u, 32), xD = __shfl_xor(D.u, 32);
            union { unsigned w[4]; bf16x8 v; } pf;
            pf.w[0] = h5 ? xC : A.u;
            pf.w[1] = h5 ? xD : B.u;
            pf.w[2] = h5 ? C.u : xA;
            pf.w[3] = h5 ? D.u : xB;
            pfrag[c] = pf.v;
        }

        // ---- PV: O[dout(reg)][q(lane)] += V^T x P  (A=V rows=dout, B=P rows=q)
        __builtin_amdgcn_s_setprio(1);
#pragma unroll
        for (int dt = 0; dt < 4; dt++) {
            int row = dt * 32 + l31;
#pragma unroll
            for (int c = 0; c < 2; c++) {
                int unit = (4 * h + 2 * c + h5) ^ (row & 7);
                bf16x8 av = *(const bf16x8*)(sV + row * 64 + unit * 8);
                o[dt] = __builtin_amdgcn_mfma_f32_32x32x16_bf16(av, pfrag[c], o[dt], 0, 0, 0);
            }
        }
        __builtin_amdgcn_s_setprio(0);
    }

    // ---- kv-half merge (once per block), obuf aliases sK/sV
    __syncthreads();                           // all LDS reads done before alias writes
    float* mlbuf = (float*)(smem + 33792);     // [s][h][{m,l}][32]
    if (lane < 32) {
        mlbuf[((s * 2 + h) * 2 + 0) * 32 + lane] = m_i;
        mlbuf[((s * 2 + h) * 2 + 1) * 32 + lane] = l_i;
    }
    __syncthreads();
    const float pm = mlbuf[((s * 2 + (h ^ 1)) * 2 + 0) * 32 + l31];
    const float pl = mlbuf[((s * 2 + (h ^ 1)) * 2 + 1) * 32 + l31];
    const float M = fmaxf(m_i, pm);
    const float sc = __expf(m_i - M), psc = __expf(pm - M);
    const float L = l_i * sc + pl * psc;
    const float fac = sc / L;
    float* obuf = (float*)smem + s * 4224;     // [32 q][132 dout-padded]
    if (h == 1) {
#pragma unroll
        for (int dt = 0; dt < 4; dt++)
#pragma unroll
            for (int e = 0; e < 16; e++) {
                int dout = dt * 32 + (e & 3) + 8 * (e >> 2) + 4 * h5;
                obuf[l31 * 132 + dout] = o[dt][e] * fac;
            }
    }
    __syncthreads();
    if (h == 0) {
#pragma unroll
        for (int dt = 0; dt < 4; dt++)
#pragma unroll
            for (int e = 0; e < 16; e++) {
                int dout = dt * 32 + (e & 3) + 8 * (e >> 2) + 4 * h5;
                int idx = l31 * 132 + dout;
                obuf[idx] = o[dt][e] * fac + obuf[idx];
            }
    }
    __syncthreads();
    // coalesced store: each wave handles 16 of the block's 64 q-rows
#pragma unroll
    for (int rr = 0; rr < 8; rr++) {
        int qblk = wave * 16 + h5 * 8 + rr;
        int ss = qblk >> 5, qq = qblk & 31;
        const float* src = (const float*)smem + ss * 4224 + qq * 132 + l31 * 4;
        float4 v4 = *(const float4*)src;
        bf16x4 ov = {(__bf16)v4.x, (__bf16)v4.y, (__bf16)v4.z, (__bf16)v4.w};
        *(bf16x4*)(ob + (size_t)(q0 + qblk) * DM + head * DH + l31 * 4) = ov;
    }
}

// ---------------- launch ----------------

extern "C" void kernel_launch(void* const* d_in, const int* in_sizes, int n_in,
                              void* d_out, int out_size, void* d_ws, size_t ws_size,
                              hipStream_t stream) {
    const float* img       = (const float*)d_in[0];
    const float* txt       = (const float*)d_in[1];
    const float* rope      = (const float*)d_in[2];
    const float* img_masks = (const float*)d_in[3];
    const float* Wq   = (const float*)d_in[4];  const float* bq   = (const float*)d_in[5];
    const float* Wk   = (const float*)d_in[6];  const float* bk   = (const float*)d_in[7];
    const float* Wv   = (const float*)d_in[8];  const float* bv   = (const float*)d_in[9];
    const float* Wo   = (const float*)d_in[10]; const float* bo   = (const float*)d_in[11];
    const float* Wq_t = (const float*)d_in[12]; const float* bq_t = (const float*)d_in[13];
    const float* Wk_t = (const float*)d_in[14]; const float* bk_t = (const float*)d_in[15];
    const float* Wv_t = (const float*)d_in[16]; const float* bv_t = (const float*)d_in[17];
    const float* Wo_t = (const float*)d_in[18]; const float* bo_t = (const float*)d_in[19];
    const float* qn   = (const float*)d_in[20]; const float* kn   = (const float*)d_in[21];
    const float* qn_t = (const float*)d_in[22]; const float* kn_t = (const float*)d_in[23];
    float* out = (float*)d_out;

    const size_t WELEM = (size_t)DM * DM;
    const size_t XELEM = (size_t)LSEQ * DM;

    __bf16* wbf  = (__bf16*)d_ws;
    __bf16* xbf  = wbf + 8 * WELEM;
    float*  qraw = (float*)(xbf + XELEM);
    float*  kraw = qraw + XELEM;
    float*  vraw = kraw + XELEM;
    __bf16* qbf  = (__bf16*)(vraw + XELEM);
    __bf16* kbf  = qbf + XELEM;
    __bf16* vt   = kbf + XELEM;
    __bf16* attnbf = (__bf16*)qraw;                // reuse (qraw dead after rmsrope)

    cvt8_kernel<<<dim3((int)(WELEM / 8 / 256), 8), 256, 0, stream>>>(
        Wq, Wk, Wv, Wo, Wq_t, Wk_t, Wv_t, Wo_t, wbf);
    cvt_kernel<<<dim3((LI * DM / 8 + 255) / 256), 256, 0, stream>>>(img, xbf, LI * DM / 8);
    cvt_kernel<<<dim3((LT * DM / 8 + 255) / 256), 256, 0, stream>>>(
        txt, xbf + (size_t)LI * DM, LT * DM / 8);

    gemm_qkv_a_kernel<<<dim3(60, 10), 256, 0, stream>>>(
        xbf, wbf, bq, bk, bv, bq_t, bk_t, bv_t, qraw, kraw, vraw);
    gemm_qkv_b_kernel<<<dim3(60, 9), 256, 0, stream>>>(
        xbf, wbf, bq, bk, bv, bq_t, bk_t, bv_t, qraw, kraw, vraw);

    rmsrope_kernel<<<dim3(LSEQ), 256, 0, stream>>>(
        qraw, kraw, rope, img_masks, qn, kn, qn_t, kn_t, qbf, kbf);

    transpose_cvt_kernel<<<dim3(DM / 32, LSEQ / 32), 256, 0, stream>>>(vraw, vt);

    flash_kernel<<<dim3(NH, LSEQ / 64), 256, 0, stream>>>(qbf, kbf, vt, attnbf);

    gemm_out_kernel<<<dim3(20, 19), 256, 0, stream>>>(attnbf, wbf, bo, bo_t, out);
}

// Round 7
// 579.413 us; speedup vs baseline: 1.0564x; 1.0075x over previous
//
#include <hip/hip_runtime.h>
#include <math.h>

#define LI 2048
#define LT 384
#define LSEQ 2432
#define DM 2560
#define NH 20
#define DH 128
#define SCALE 0.08838834764831845f
#define CEXP (SCALE * 1.4426950408889634f)
#define NKV 38

typedef __bf16 bf16x8 __attribute__((ext_vector_type(8)));
typedef __bf16 bf16x4 __attribute__((ext_vector_type(4)));
typedef __bf16 bf16x2 __attribute__((ext_vector_type(2)));
typedef float f32x4 __attribute__((ext_vector_type(4)));
typedef float f32x16 __attribute__((ext_vector_type(16)));

__device__ __forceinline__ void async_copy16(const void* gsrc, void* lds_uniform) {
    __builtin_amdgcn_global_load_lds(
        (const __attribute__((address_space(1))) unsigned int*)gsrc,
        (__attribute__((address_space(3))) unsigned int*)lds_uniform,
        16, 0, 0);
}

// ---------------- f32 -> bf16 conversions ----------------

__global__ __launch_bounds__(256) void cvt8_kernel(
    const float* __restrict__ s0, const float* __restrict__ s1,
    const float* __restrict__ s2, const float* __restrict__ s3,
    const float* __restrict__ s4, const float* __restrict__ s5,
    const float* __restrict__ s6, const float* __restrict__ s7,
    __bf16* __restrict__ dst)
{
    const float* srcs[8] = {s0, s1, s2, s3, s4, s5, s6, s7};
    const float* s = srcs[blockIdx.y];
    __bf16* d = dst + (size_t)blockIdx.y * (size_t)DM * DM;
    int i = blockIdx.x * 256 + threadIdx.x;
    const float4* sp = (const float4*)s + (size_t)i * 2;
    float4 a = sp[0], b = sp[1];
    bf16x8 o = {(__bf16)a.x, (__bf16)a.y, (__bf16)a.z, (__bf16)a.w,
                (__bf16)b.x, (__bf16)b.y, (__bf16)b.z, (__bf16)b.w};
    *((bf16x8*)d + i) = o;
}

__global__ __launch_bounds__(256) void cvt_kernel(
    const float* __restrict__ s, __bf16* __restrict__ d, int n8)
{
    int i = blockIdx.x * 256 + threadIdx.x;
    if (i >= n8) return;
    const float4* sp = (const float4*)s + (size_t)i * 2;
    float4 a = sp[0], b = sp[1];
    bf16x8 o = {(__bf16)a.x, (__bf16)a.y, (__bf16)a.z, (__bf16)a.w,
                (__bf16)b.x, (__bf16)b.y, (__bf16)b.z, (__bf16)b.w};
    *((bf16x8*)d + i) = o;
}

// ---------------- 128x128 bf16 GEMM core, BK=64, XOR-swizzled LDS ----------------

__device__ __forceinline__ void gemm_core(
    const __bf16* __restrict__ Ab,
    const __bf16* __restrict__ Bb,
    const float* __restrict__ bias,
    float* __restrict__ Cb,
    __bf16* sA, __bf16* sB)
{
    const int t = threadIdx.x, wave = t >> 6, lane = t & 63;
    const int l15 = lane & 15, quad = lane >> 4;
    const int wm = wave >> 1, wn = wave & 1;

    f32x4 acc[4][4];
#pragma unroll
    for (int i = 0; i < 4; i++)
#pragma unroll
        for (int j = 0; j < 4; j++) acc[i][j] = f32x4{0.f, 0.f, 0.f, 0.f};

    size_t soff[4];
#pragma unroll
    for (int j = 0; j < 4; j++) {
        int c = j * 256 + t;
        int row = c >> 3, u = c & 7;
        soff[j] = (size_t)row * DM + ((u ^ (row & 7)) * 8);
    }

    for (int k0 = 0; k0 < DM; k0 += 64) {
        __syncthreads();
#pragma unroll
        for (int j = 0; j < 4; j++)
            async_copy16(Ab + soff[j] + k0, (char*)sA + (j * 256 + wave * 64) * 16);
#pragma unroll
        for (int j = 0; j < 4; j++)
            async_copy16(Bb + soff[j] + k0, (char*)sB + (j * 256 + wave * 64) * 16);
        __syncthreads();

#pragma unroll
        for (int ks = 0; ks < 2; ks++) {
            bf16x8 af[4], bg[4];
#pragma unroll
            for (int mt = 0; mt < 4; mt++) {
                int r = wm * 64 + mt * 16 + l15;
                af[mt] = *(const bf16x8*)(sA + r * 64 + (((quad + ks * 4) ^ (r & 7)) * 8));
            }
#pragma unroll
            for (int nt = 0; nt < 4; nt++) {
                int r = wn * 64 + nt * 16 + l15;
                bg[nt] = *(const bf16x8*)(sB + r * 64 + (((quad + ks * 4) ^ (r & 7)) * 8));
            }
#pragma unroll
            for (int mt = 0; mt < 4; mt++)
#pragma unroll
                for (int nt = 0; nt < 4; nt++)
                    acc[mt][nt] = __builtin_amdgcn_mfma_f32_16x16x32_bf16(af[mt], bg[nt], acc[mt][nt], 0, 0, 0);
        }
    }

#pragma unroll
    for (int mt = 0; mt < 4; mt++) {
        const int row = wm * 64 + mt * 16 + quad * 4;
#pragma unroll
        for (int nt = 0; nt < 4; nt++) {
            const int col = wn * 64 + nt * 16 + l15;
            const float bv = bias[col];
            float* cp = Cb + (size_t)row * DM + col;
            cp[0]        = acc[mt][nt][0] + bv;
            cp[DM]       = acc[mt][nt][1] + bv;
            cp[2 * DM]   = acc[mt][nt][2] + bv;
            cp[3 * DM]   = acc[mt][nt][3] + bv;
        }
    }
}

// QKV: grid (60, 19), R0 mapping (n fastest) — measured best.
__global__ __launch_bounds__(256, 4) void gemm_qkv_kernel(
    const __bf16* __restrict__ xbf, const __bf16* __restrict__ wbf,
    const float* __restrict__ bq, const float* __restrict__ bk, const float* __restrict__ bv,
    const float* __restrict__ bq_t, const float* __restrict__ bk_t, const float* __restrict__ bv_t,
    float* __restrict__ qraw, float* __restrict__ kraw, float* __restrict__ vraw)
{
    __shared__ alignas(16) __bf16 sA[128 * 64];
    __shared__ alignas(16) __bf16 sB[128 * 64];
    const int nblk = blockIdx.x, mblk = blockIdx.y;
    const int which = nblk / 20;               // 0=Q 1=K 2=V
    const int nloc = (nblk % 20) * 128;
    const bool is_txt = (mblk >= 16);
    const size_t WELEM = (size_t)DM * DM;
    const int widx = which + (is_txt ? 4 : 0);
    const __bf16* W = wbf + (size_t)widx * WELEM;
    const float* bias = (which == 0) ? (is_txt ? bq_t : bq)
                      : (which == 1) ? (is_txt ? bk_t : bk)
                                     : (is_txt ? bv_t : bv);
    float* C = (which == 0) ? qraw : (which == 1) ? kraw : vraw;
    gemm_core(xbf + (size_t)mblk * 128 * DM, W + (size_t)nloc * DM, bias + nloc,
              C + (size_t)mblk * 128 * DM + nloc, sA, sB);
}

// Out-proj: grid (20, 19), R0 mapping.
__global__ __launch_bounds__(256, 4) void gemm_out_kernel(
    const __bf16* __restrict__ attnbf, const __bf16* __restrict__ wbf,
    const float* __restrict__ bo, const float* __restrict__ bo_t,
    float* __restrict__ out)
{
    __shared__ alignas(16) __bf16 sA[128 * 64];
    __shared__ alignas(16) __bf16 sB[128 * 64];
    const int nblk = blockIdx.x, mblk = blockIdx.y;
    const bool is_txt = (mblk >= 16);
    const size_t WELEM = (size_t)DM * DM;
    const __bf16* W = wbf + (size_t)(is_txt ? 7 : 3) * WELEM;
    const float* bias = (is_txt ? bo_t : bo) + nblk * 128;
    gemm_core(attnbf + (size_t)mblk * 128 * DM, W + (size_t)nblk * 128 * DM, bias,
              out + (size_t)mblk * 128 * DM + nblk * 128, sA, sB);
}

// ---------------- RMS norm + qn/kn + mask + RoPE, f32 -> bf16 ----------------

__global__ __launch_bounds__(256) void rmsrope_kernel(
    const float* __restrict__ qraw, const float* __restrict__ kraw,
    const float* __restrict__ rope, const float* __restrict__ img_masks,
    const float* __restrict__ qn, const float* __restrict__ kn,
    const float* __restrict__ qn_t, const float* __restrict__ kn_t,
    __bf16* __restrict__ qbf, __bf16* __restrict__ kbf)
{
    const int l = blockIdx.x, t = threadIdx.x;
    const int wave = t >> 6, lane = t & 63;
    const bool is_img = (l < LI);
    const float* qw = is_img ? qn : qn_t;
    const float* kw = is_img ? kn : kn_t;
    const float kmask = is_img ? img_masks[l] : 1.0f;
    const float* qr = qraw + (size_t)l * DM;
    const float* kr = kraw + (size_t)l * DM;

    float2 qv[5], kv[5];
    float sq = 0.f, sk = 0.f;
#pragma unroll
    for (int j = 0; j < 5; j++) {
        int c2 = j * 256 + t;
        qv[j] = *(const float2*)(qr + 2 * c2);
        kv[j] = *(const float2*)(kr + 2 * c2);
        sq += qv[j].x * qv[j].x + qv[j].y * qv[j].y;
        sk += kv[j].x * kv[j].x + kv[j].y * kv[j].y;
    }
#pragma unroll
    for (int m = 32; m; m >>= 1) { sq += __shfl_xor(sq, m); sk += __shfl_xor(sk, m); }
    __shared__ float redq[4], redk[4];
    if (lane == 0) { redq[wave] = sq; redk[wave] = sk; }
    __syncthreads();
    sq = redq[0] + redq[1] + redq[2] + redq[3];
    sk = redk[0] + redk[1] + redk[2] + redk[3];
    const float rq = rsqrtf(sq * (1.0f / DM) + 1e-5f);
    const float rk = rsqrtf(sk * (1.0f / DM) + 1e-5f) * kmask;

#pragma unroll
    for (int j = 0; j < 5; j++) {
        int c2 = j * 256 + t;
        int c = 2 * c2;
        float4 rp = *(const float4*)(rope + ((size_t)l * 64 + (c2 & 63)) * 4);
        float2 w2q = *(const float2*)(qw + c);
        float2 w2k = *(const float2*)(kw + c);
        float x0 = qv[j].x * rq * w2q.x, x1 = qv[j].y * rq * w2q.y;
        bf16x2 oq = {(__bf16)(rp.x * x0 + rp.y * x1), (__bf16)(rp.z * x0 + rp.w * x1)};
        *(bf16x2*)(qbf + (size_t)l * DM + c) = oq;
        float y0 = kv[j].x * rk * w2k.x, y1 = kv[j].y * rk * w2k.y;
        bf16x2 ok = {(__bf16)(rp.x * y0 + rp.y * y1), (__bf16)(rp.z * y0 + rp.w * y1)};
        *(bf16x2*)(kbf + (size_t)l * DM + c) = ok;
    }
}

// ---------------- transpose V (L,DM) f32 -> (DM,L) bf16 ----------------

__global__ __launch_bounds__(256) void transpose_cvt_kernel(
    const float* __restrict__ src, __bf16* __restrict__ dst)
{
    __shared__ float tile[32][33];
    const int c0 = blockIdx.x * 32;
    const int r0 = blockIdx.y * 32;
    const int tc = threadIdx.x & 31, tr = threadIdx.x >> 5;
#pragma unroll
    for (int j = 0; j < 4; j++)
        tile[tr + j * 8][tc] = src[(size_t)(r0 + tr + j * 8) * DM + c0 + tc];
    __syncthreads();
#pragma unroll
    for (int j = 0; j < 4; j++)
        dst[(size_t)(c0 + tr + j * 8) * LSEQ + r0 + tc] = (__bf16)tile[tc][tr + j * 8];
}

// ---------------- flash attention v4: 32x32 MFMA + kv-split + K-ahead + T13 ----------------
// v3 structure (32x32 MFMA, in-register P, kv-half merge) plus:
//  - K double-buffered (2x16K), V single (16K) -> 48K LDS, 3 blocks/CU retained.
//    Per iter: [vmcnt0+barA] issue V_it; QK^T+softmax (hides V latency);
//    [vmcnt0+barB] issue K_{it+1} into kbuf^1; P-assembly+PV (hides K latency).
//    At barA only K_it in flight; at barB only V_it. WARs closed by the barriers.
//  - T13 defer-rescale (THR=90 raw = 8 post-scale): skip 64-mul O-rescale when
//    tile max doesn't grow; SCALE folded into exp2 (p = exp2(st*C - m*C)).

__global__ __launch_bounds__(256, 3) void flash_kernel(
    const __bf16* __restrict__ qb, const __bf16* __restrict__ kb,
    const __bf16* __restrict__ vt, __bf16* __restrict__ ob)
{
    __shared__ alignas(16) char smem[49152];   // kbuf0 16K | kbuf1 16K | vbuf 16K
    const int head = blockIdx.x;
    const int q0 = blockIdx.y * 64;
    const int t = threadIdx.x, wave = t >> 6, lane = t & 63;
    const int s = wave >> 1, h = wave & 1;
    const int l31 = lane & 31, h5 = lane >> 5;

    bf16x8 bq8[8];
    {
        const __bf16* qp = qb + (size_t)(q0 + s * 32 + l31) * DM + head * DH;
#pragma unroll
        for (int t8 = 0; t8 < 8; t8++)
            bq8[t8] = *(const bf16x8*)(qp + t8 * 16 + h5 * 8);
    }

    int koff[4], voff[4];
#pragma unroll
    for (int j = 0; j < 4; j++) {
        int c = j * 256 + t;
        int krow = c >> 4, ku = (c & 15) ^ (krow & 7);
        koff[j] = krow * DM + head * DH + ku * 8;
        int vrow = c >> 3, vu = (c & 7) ^ (vrow & 7);
        voff[j] = (head * DH + vrow) * LSEQ + vu * 8;
    }
    const int dunit = wave * 1024;          // HW adds lane*16
    const int kbase = 32 * h;

    f32x16 o[4];
#pragma unroll
    for (int dt = 0; dt < 4; dt++)
#pragma unroll
        for (int e = 0; e < 16; e++) o[dt][e] = 0.f;
    float m_i = -INFINITY, l_i = 0.f, mc = 0.f;

    // prologue: K_0 -> kbuf0
#pragma unroll
    for (int j = 0; j < 4; j++)
        async_copy16(kb + koff[j], smem + j * 4096 + dunit);

    for (int it = 0; it < NKV; ++it) {
        const __bf16* sK = (const __bf16*)(smem + (it & 1) * 16384);
        const __bf16* sV = (const __bf16*)(smem + 32768);

        // K_it landed (only in-flight stream) + visible to all waves; closes PV(it-1)
        asm volatile("s_waitcnt vmcnt(0)\n\ts_barrier" ::: "memory");

        // issue V_it (vbuf safe: prev PV closed); latency hides under QK^T+softmax
#pragma unroll
        for (int j = 0; j < 4; j++)
            async_copy16(vt + voff[j] + it * 64, smem + 32768 + j * 4096 + dunit);

        // ---- QK^T: st[kv(reg)][q(lane)] over this wave's 32-kv half
        f32x16 st;
#pragma unroll
        for (int e = 0; e < 16; e++) st[e] = 0.f;
        __builtin_amdgcn_s_setprio(1);
#pragma unroll
        for (int t8 = 0; t8 < 8; t8++) {
            int row = kbase + l31;
            int unit = (2 * t8 + h5) ^ (row & 7);
            bf16x8 ak = *(const bf16x8*)(sK + row * 128 + unit * 8);
            st = __builtin_amdgcn_mfma_f32_32x32x16_bf16(ak, bq8[t8], st, 0, 0, 0);
        }
        __builtin_amdgcn_s_setprio(0);

        // ---- softmax with T13 defer-rescale (raw domain; SCALE folded into exp2)
        float pmax = st[0];
#pragma unroll
        for (int e = 1; e < 16; e++) pmax = fmaxf(pmax, st[e]);
        pmax = fmaxf(pmax, __shfl_xor(pmax, 32));
        if (!__all(pmax <= m_i + 90.0f)) {
            const float mnew = fmaxf(m_i, pmax);
            const float al = exp2f((m_i - mnew) * CEXP);
            m_i = mnew; mc = mnew * CEXP;
#pragma unroll
            for (int dt = 0; dt < 4; dt++)
#pragma unroll
                for (int e = 0; e < 16; e++) o[dt][e] *= al;
            l_i *= al;
        }
        float sum = 0.f;
#pragma unroll
        for (int e = 0; e < 16; e++) {
            float p = exp2f(st[e] * CEXP - mc);
            st[e] = p; sum += p;
        }
        sum += __shfl_xor(sum, 32);
        l_i += sum;

        // V_it landed + visible; closes QK^T reads of sK
        asm volatile("s_waitcnt vmcnt(0)\n\ts_barrier" ::: "memory");

        // issue K_{it+1} into the other K buffer (its readers closed at barB(it-1));
        // latency hides under P-assembly + PV
        if (it + 1 < NKV) {
#pragma unroll
            for (int j = 0; j < 4; j++)
                async_copy16(kb + koff[j] + (size_t)((it + 1) * 64) * DM,
                             smem + ((it + 1) & 1) * 16384 + j * 4096 + dunit);
        }

        // ---- P fragments in-register
        bf16x8 pfrag[2];
#pragma unroll
        for (int c = 0; c < 2; c++) {
            union { bf16x2 v; unsigned u; } A, B, C, D;
            A.v = bf16x2{(__bf16)st[8 * c + 0], (__bf16)st[8 * c + 1]};
            B.v = bf16x2{(__bf16)st[8 * c + 2], (__bf16)st[8 * c + 3]};
            C.v = bf16x2{(__bf16)st[8 * c + 4], (__bf16)st[8 * c + 5]};
            D.v = bf16x2{(__bf16)st[8 * c + 6], (__bf16)st[8 * c + 7]};
            unsigned xA = __shfl_xor(A.u, 32), xB = __shfl_xor(B.u, 32);
            unsigned xC = __shfl_xor(C.u, 32), xD = __shfl_xor(D.u, 32);
            union { unsigned w[4]; bf16x8 v; } pf;
            pf.w[0] = h5 ? xC : A.u;
            pf.w[1] = h5 ? xD : B.u;
            pf.w[2] = h5 ? C.u : xA;
            pf.w[3] = h5 ? D.u : xB;
            pfrag[c] = pf.v;
        }

        // ---- PV: O[dout(reg)][q(lane)] += V^T x P
        __builtin_amdgcn_s_setprio(1);
#pragma unroll
        for (int dt = 0; dt < 4; dt++) {
            int row = dt * 32 + l31;
#pragma unroll
            for (int c = 0; c < 2; c++) {
                int unit = (4 * h + 2 * c + h5) ^ (row & 7);
                bf16x8 av = *(const bf16x8*)(sV + row * 64 + unit * 8);
                o[dt] = __builtin_amdgcn_mfma_f32_32x32x16_bf16(av, pfrag[c], o[dt], 0, 0, 0);
            }
        }
        __builtin_amdgcn_s_setprio(0);
    }

    // ---- kv-half merge (once per block), buffers alias main-loop LDS
    __syncthreads();                           // all LDS reads done before alias writes
    float* mlbuf = (float*)(smem + 33792);     // [s][h][{m,l}][32]
    if (lane < 32) {
        mlbuf[((s * 2 + h) * 2 + 0) * 32 + lane] = m_i;
        mlbuf[((s * 2 + h) * 2 + 1) * 32 + lane] = l_i;
    }
    __syncthreads();
    const float pm = mlbuf[((s * 2 + (h ^ 1)) * 2 + 0) * 32 + l31];
    const float pl = mlbuf[((s * 2 + (h ^ 1)) * 2 + 1) * 32 + l31];
    const float M = fmaxf(m_i, pm);
    const float sc = exp2f((m_i - M) * CEXP), psc = exp2f((pm - M) * CEXP);
    const float L = l_i * sc + pl * psc;
    const float fac = sc / L;
    float* obuf = (float*)smem + s * 4224;     // [32 q][132 dout-padded]
    if (h == 1) {
#pragma unroll
        for (int dt = 0; dt < 4; dt++)
#pragma unroll
            for (int e = 0; e < 16; e++) {
                int dout = dt * 32 + (e & 3) + 8 * (e >> 2) + 4 * h5;
                obuf[l31 * 132 + dout] = o[dt][e] * fac;
            }
    }
    __syncthreads();
    if (h == 0) {
#pragma unroll
        for (int dt = 0; dt < 4; dt++)
#pragma unroll
            for (int e = 0; e < 16; e++) {
                int dout = dt * 32 + (e & 3) + 8 * (e >> 2) + 4 * h5;
                int idx = l31 * 132 + dout;
                obuf[idx] = o[dt][e] * fac + obuf[idx];
            }
    }
    __syncthreads();
#pragma unroll
    for (int rr = 0; rr < 8; rr++) {
        int qblk = wave * 16 + h5 * 8 + rr;
        int ss = qblk >> 5, qq = qblk & 31;
        const float* src = (const float*)smem + ss * 4224 + qq * 132 + l31 * 4;
        float4 v4 = *(const float4*)src;
        bf16x4 ov = {(__bf16)v4.x, (__bf16)v4.y, (__bf16)v4.z, (__bf16)v4.w};
        *(bf16x4*)(ob + (size_t)(q0 + qblk) * DM + head * DH + l31 * 4) = ov;
    }
}

// ---------------- launch ----------------

extern "C" void kernel_launch(void* const* d_in, const int* in_sizes, int n_in,
                              void* d_out, int out_size, void* d_ws, size_t ws_size,
                              hipStream_t stream) {
    const float* img       = (const float*)d_in[0];
    const float* txt       = (const float*)d_in[1];
    const float* rope      = (const float*)d_in[2];
    const float* img_masks = (const float*)d_in[3];
    const float* Wq   = (const float*)d_in[4];  const float* bq   = (const float*)d_in[5];
    const float* Wk   = (const float*)d_in[6];  const float* bk   = (const float*)d_in[7];
    const float* Wv   = (const float*)d_in[8];  const float* bv   = (const float*)d_in[9];
    const float* Wo   = (const float*)d_in[10]; const float* bo   = (const float*)d_in[11];
    const float* Wq_t = (const float*)d_in[12]; const float* bq_t = (const float*)d_in[13];
    const float* Wk_t = (const float*)d_in[14]; const float* bk_t = (const float*)d_in[15];
    const float* Wv_t = (const float*)d_in[16]; const float* bv_t = (const float*)d_in[17];
    const float* Wo_t = (const float*)d_in[18]; const float* bo_t = (const float*)d_in[19];
    const float* qn   = (const float*)d_in[20]; const float* kn   = (const float*)d_in[21];
    const float* qn_t = (const float*)d_in[22]; const float* kn_t = (const float*)d_in[23];
    float* out = (float*)d_out;

    const size_t WELEM = (size_t)DM * DM;
    const size_t XELEM = (size_t)LSEQ * DM;

    __bf16* wbf  = (__bf16*)d_ws;
    __bf16* xbf  = wbf + 8 * WELEM;
    float*  qraw = (float*)(xbf + XELEM);
    float*  kraw = qraw + XELEM;
    float*  vraw = kraw + XELEM;
    __bf16* qbf  = (__bf16*)(vraw + XELEM);
    __bf16* kbf  = qbf + XELEM;
    __bf16* vt   = kbf + XELEM;
    __bf16* attnbf = (__bf16*)qraw;                // reuse (qraw dead after rmsrope)

    cvt8_kernel<<<dim3((int)(WELEM / 8 / 256), 8), 256, 0, stream>>>(
        Wq, Wk, Wv, Wo, Wq_t, Wk_t, Wv_t, Wo_t, wbf);
    cvt_kernel<<<dim3((LI * DM / 8 + 255) / 256), 256, 0, stream>>>(img, xbf, LI * DM / 8);
    cvt_kernel<<<dim3((LT * DM / 8 + 255) / 256), 256, 0, stream>>>(
        txt, xbf + (size_t)LI * DM, LT * DM / 8);

    gemm_qkv_kernel<<<dim3(60, 19), 256, 0, stream>>>(
        xbf, wbf, bq, bk, bv, bq_t, bk_t, bv_t, qraw, kraw, vraw);

    rmsrope_kernel<<<dim3(LSEQ), 256, 0, stream>>>(
        qraw, kraw, rope, img_masks, qn, kn, qn_t, kn_t, qbf, kbf);

    transpose_cvt_kernel<<<dim3(DM / 32, LSEQ / 32), 256, 0, stream>>>(vraw, vt);

    flash_kernel<<<dim3(NH, LSEQ / 64), 256, 0, stream>>>(qbf, kbf, vt, attnbf);

    gemm_out_kernel<<<dim3(20, 19), 256, 0, stream>>>(attnbf, wbf, bo, bo_t, out);
}